// Round 1
// baseline (20486.853 us; speedup 1.0000x reference)
//
#include <hip/hip_runtime.h>
#include <stdint.h>
#include <math.h>

#define NV 8192
#define EMB 512
#define CLS 257
#define DEG 32
#define TV 16

// ---------------------------------------------------------------------------
// Threefry-2x32, 20 rounds — exactly JAX's _threefry2x32.
// Key schedule ks = [k0, k1, k0^k1^0x1BD11BDA]; input x=(x0,x1)=(hi,lo).
// ---------------------------------------------------------------------------
__device__ __forceinline__ void tf20(uint32_t k0, uint32_t k1,
                                     uint32_t x0, uint32_t x1,
                                     uint32_t& o0, uint32_t& o1) {
  const uint32_t ks2 = k0 ^ k1 ^ 0x1BD11BDAu;
  uint32_t v0 = x0 + k0, v1 = x1 + k1;
#define QR(r) { v0 += v1; v1 = (v1 << (r)) | (v1 >> (32 - (r))); v1 ^= v0; }
  QR(13) QR(15) QR(26) QR(6)
  v0 += k1;  v1 += ks2 + 1u;
  QR(17) QR(29) QR(16) QR(24)
  v0 += ks2; v1 += k0 + 2u;
  QR(13) QR(15) QR(26) QR(6)
  v0 += k0;  v1 += k1 + 3u;
  QR(17) QR(29) QR(16) QR(24)
  v0 += k1;  v1 += ks2 + 4u;
  QR(13) QR(15) QR(26) QR(6)
  v0 += ks2; v1 += k0 + 5u;
#undef QR
  o0 = v0; o1 = v1;
}

// ---------------------------------------------------------------------------
// K1: graph_emb = mean(embeddings, axis=0), deterministic two-pass reduction
// ---------------------------------------------------------------------------
__global__ __launch_bounds__(256) void colmean_part(const float* __restrict__ emb,
                                                    float* __restrict__ part) {
  const int b = blockIdx.x;          // 64 blocks x 128 rows
  const int t = threadIdx.x;
  for (int j = t; j < EMB; j += 256) {
    float s = 0.f;
    const int r0 = b * 128;
    for (int r = 0; r < 128; ++r) s += emb[(size_t)(r0 + r) * EMB + j];
    part[(size_t)b * EMB + j] = s;
  }
}

__global__ __launch_bounds__(256) void colmean_fin(const float* __restrict__ part,
                                                   float* __restrict__ g) {
  const int t = threadIdx.x;
  for (int j = t; j < EMB; j += 256) {
    float s = 0.f;
    for (int b = 0; b < 64; ++b) s += part[(size_t)b * EMB + j];
    g[j] = s / 8192.0f;
  }
}

// ---------------------------------------------------------------------------
// K2: fused 3-layer MLP for a tile of TV=16 vertices per block.
// x = concat(emb[v], graph_emb); h1 = leaky(x@W1+b1); h2 = leaky(h1@W2+b2);
// logits = h2@W3+b3. Chunked (64-wide) fp32 accumulation for accuracy.
// ---------------------------------------------------------------------------
__global__ __launch_bounds__(256) void mlp3(
    const float* __restrict__ emb, const float* __restrict__ g,
    const float* __restrict__ W1, const float* __restrict__ b1,
    const float* __restrict__ W2, const float* __restrict__ b2,
    const float* __restrict__ W3, const float* __restrict__ b3,
    float* __restrict__ logits)
{
  __shared__ float xs[TV][68];       // staged emb chunk [16][64] (+pad)
  __shared__ float gs[EMB];          // graph_emb
  __shared__ float h1s[TV][EMB];     // 32 KB
  __shared__ float h2s[TV][400];     // 25.6 KB

  const int t  = threadIdx.x;
  const int tx = t & 63;
  const int ty = t >> 6;
  const int v0 = blockIdx.x * TV;

  for (int j = t; j < EMB; j += 256) gs[j] = g[j];

  // ---- layer 1, emb half (k < 512): each thread -> 4 vertices x 8 cols ----
  float acc[4][8];
#pragma unroll
  for (int a = 0; a < 4; ++a)
#pragma unroll
    for (int b = 0; b < 8; ++b) acc[a][b] = 0.f;

  for (int kc = 0; kc < 8; ++kc) {
    __syncthreads();
    {
      const int vv = t >> 4;
      const int kk = (t & 15) << 2;
      const float4 s4 = *reinterpret_cast<const float4*>(
          &emb[(size_t)(v0 + vv) * EMB + kc * 64 + kk]);
      xs[vv][kk] = s4.x; xs[vv][kk + 1] = s4.y;
      xs[vv][kk + 2] = s4.z; xs[vv][kk + 3] = s4.w;
    }
    __syncthreads();
    float cacc[4][8];
#pragma unroll
    for (int a = 0; a < 4; ++a)
#pragma unroll
      for (int b = 0; b < 8; ++b) cacc[a][b] = 0.f;
    for (int kk = 0; kk < 64; ++kk) {
      const int k = kc * 64 + kk;
      float w[8];
#pragma unroll
      for (int jj = 0; jj < 8; ++jj) w[jj] = W1[(size_t)k * EMB + tx + 64 * jj];
      float xv[4];
#pragma unroll
      for (int vv = 0; vv < 4; ++vv) xv[vv] = xs[ty * 4 + vv][kk];
#pragma unroll
      for (int vv = 0; vv < 4; ++vv)
#pragma unroll
        for (int jj = 0; jj < 8; ++jj)
          cacc[vv][jj] = fmaf(xv[vv], w[jj], cacc[vv][jj]);
    }
#pragma unroll
    for (int a = 0; a < 4; ++a)
#pragma unroll
      for (int b = 0; b < 8; ++b) acc[a][b] += cacc[a][b];
  }

  // ---- layer 1, graph_emb half (k >= 512): same for every vertex ----
  float gacc[8];
#pragma unroll
  for (int b = 0; b < 8; ++b) gacc[b] = 0.f;
  for (int kc = 0; kc < 8; ++kc) {
    float cg[8];
#pragma unroll
    for (int b = 0; b < 8; ++b) cg[b] = 0.f;
    for (int kk = 0; kk < 64; ++kk) {
      const int k = kc * 64 + kk;
      const float gv = gs[k];
#pragma unroll
      for (int jj = 0; jj < 8; ++jj)
        cg[jj] = fmaf(gv, W1[(size_t)(EMB + k) * EMB + tx + 64 * jj], cg[jj]);
    }
#pragma unroll
    for (int b = 0; b < 8; ++b) gacc[b] += cg[b];
  }

#pragma unroll
  for (int jj = 0; jj < 8; ++jj) {
    const int j = tx + 64 * jj;
    const float bj = b1[j];
#pragma unroll
    for (int vv = 0; vv < 4; ++vv) {
      float h = (acc[vv][jj] + gacc[jj]) + bj;
      h = (h >= 0.f) ? h : 0.01f * h;
      h1s[ty * 4 + vv][j] = h;
    }
  }
  __syncthreads();

  // ---- layer 2: j2 in {t, t+256}, all 16 vertices per thread ----
  const int j2a = t;
  const int j2b = t + 256;
  float a2[TV], a2b[TV];
#pragma unroll
  for (int vv = 0; vv < TV; ++vv) { a2[vv] = 0.f; a2b[vv] = 0.f; }
  for (int kc = 0; kc < 8; ++kc) {
    float c2[TV], c2b[TV];
#pragma unroll
    for (int vv = 0; vv < TV; ++vv) { c2[vv] = 0.f; c2b[vv] = 0.f; }
    for (int kk = 0; kk < 64; ++kk) {
      const int k = kc * 64 + kk;
      const float w0  = W2[(size_t)k * 400 + j2a];
      const float w1v = (j2b < 400) ? W2[(size_t)k * 400 + j2b] : 0.f;
#pragma unroll
      for (int vv = 0; vv < TV; ++vv) {
        const float hv = h1s[vv][k];
        c2[vv]  = fmaf(hv, w0,  c2[vv]);
        c2b[vv] = fmaf(hv, w1v, c2b[vv]);
      }
    }
#pragma unroll
    for (int vv = 0; vv < TV; ++vv) { a2[vv] += c2[vv]; a2b[vv] += c2b[vv]; }
  }
  {
    const float bja = b2[j2a];
#pragma unroll
    for (int vv = 0; vv < TV; ++vv) {
      float h = a2[vv] + bja;
      h2s[vv][j2a] = (h >= 0.f) ? h : 0.01f * h;
    }
    if (j2b < 400) {
      const float bjb = b2[j2b];
#pragma unroll
      for (int vv = 0; vv < TV; ++vv) {
        float h = a2b[vv] + bjb;
        h2s[vv][j2b] = (h >= 0.f) ? h : 0.01f * h;
      }
    }
  }
  __syncthreads();

  // ---- layer 3: j3 = t (class 256 handled by t==0) ----
  float a3[TV], a3x[TV];
#pragma unroll
  for (int vv = 0; vv < TV; ++vv) { a3[vv] = 0.f; a3x[vv] = 0.f; }
  for (int kc = 0; kc < 8; ++kc) {
    float c3[TV], c3x[TV];
#pragma unroll
    for (int vv = 0; vv < TV; ++vv) { c3[vv] = 0.f; c3x[vv] = 0.f; }
    for (int kk = 0; kk < 50; ++kk) {
      const int k = kc * 50 + kk;
      const float w0 = W3[(size_t)k * CLS + t];
      const float wx = (t == 0) ? W3[(size_t)k * CLS + 256] : 0.f;
#pragma unroll
      for (int vv = 0; vv < TV; ++vv) {
        const float hv = h2s[vv][k];
        c3[vv]  = fmaf(hv, w0, c3[vv]);
        c3x[vv] = fmaf(hv, wx, c3x[vv]);
      }
    }
#pragma unroll
    for (int vv = 0; vv < TV; ++vv) { a3[vv] += c3[vv]; a3x[vv] += c3x[vv]; }
  }
  {
    const float bj = b3[t];
#pragma unroll
    for (int vv = 0; vv < TV; ++vv)
      logits[(size_t)(v0 + vv) * CLS + t] = a3[vv] + bj;
    if (t == 0) {
      const float bx = b3[256];
#pragma unroll
      for (int vv = 0; vv < TV; ++vv)
        logits[(size_t)(v0 + vv) * CLS + 256] = a3x[vv] + bx;
    }
  }
}

// ---------------------------------------------------------------------------
// K3: sequential sampling scan. One block, 320 threads (5 waves).
// Per step: foldlike split (partitionable threefry), 257 gumbels,
// masked gumbel-argmax (first-index tie-break), softmax prob of sampled class,
// color/n_used/logp updates. Colors kept in LDS.
// ---------------------------------------------------------------------------
__global__ __launch_bounds__(320) void scan_kernel(
    const int* __restrict__ nbr, const float* __restrict__ logits,
    const float* __restrict__ baseline, float* __restrict__ out)
{
  __shared__ int colors[NV];         // 32 KB
  __shared__ unsigned banned[9];     // 288-bit adjacency ban mask
  __shared__ float redv[5];
  __shared__ int   redi[5];
  __shared__ float redm[5];
  __shared__ float reds[5];
  __shared__ unsigned key0s, key1s, sk0s, sk1s;
  __shared__ int raws;
  __shared__ float ms;
  __shared__ float praws;
  __shared__ int nuseds;
  __shared__ float logps;

  const int t = threadIdx.x;
  for (int i = t; i < NV; i += 320) colors[i] = -1;
  if (t == 0) {
    colors[0] = 0; nuseds = 1; logps = 0.f;
    key0s = 0u; key1s = 42u;       // jax.random.key(42) -> (hi=0, lo=42)
  }
  __syncthreads();

  for (int v = 1; v < NV; ++v) {
    // ---- P0: split key (lanes 0,1 of wave 0), load nb colors, zero mask ----
    int myc = -2;
    if (t < 2) {
      uint32_t o0, o1;
      const uint32_t k0 = key0s, k1 = key1s;
      tf20(k0, k1, 0u, (uint32_t)t, o0, o1);       // counter (hi=0, lo=t)
      if (t == 0) { key0s = o0; key1s = o1; }      // keys[0] = new carry key
      else        { sk0s  = o0; sk1s  = o1; }      // keys[1] = subkey
    } else if (t >= 64 && t < 96) {
      myc = colors[nbr[(size_t)v * DEG + (t - 64)]];
    } else if (t >= 257 && t < 266) {
      banned[t - 257] = 0u;
    }
    __syncthreads();

    // ---- P1: adjacency ban scatter + gumbel noise per class ----
    if (t >= 64 && t < 96 && myc >= 0)
      atomicOr(&banned[myc >> 5], 1u << (myc & 31));

    float li = 0.f, gi = 0.f;
    if (t < CLS) {
      li = logits[(size_t)v * CLS + t];
      uint32_t o0, o1;
      tf20(sk0s, sk1s, 0u, (uint32_t)t, o0, o1);   // counter (0, class)
      const uint32_t bb = o0 ^ o1;                 // partitionable 32-bit draw
      const float f = __uint_as_float(0x3f800000u | (bb >> 9)) - 1.0f;
      const float u = fmaxf(1.17549435e-38f, f);   // minval = f32 tiny
      gi = -logf(-logf(u));
    }
    __syncthreads();

    // ---- P2: mask + (argmax of logits+gumbel, max of masked logits) ----
    bool msk = true;
    float lm = -INFINITY, lv = -INFINITY;
    int idx = t;
    const int nu = nuseds;
    if (t < CLS) {
      const bool bb  = (banned[t >> 5] >> (t & 31)) & 1u;
      const bool irr = (t >= nu) && (t < 256);
      msk = bb || irr;
      if (!msk) { lm = li; lv = li + gi; }
    }
#pragma unroll
    for (int off = 32; off > 0; off >>= 1) {
      const float ov = __shfl_down(lv, off);
      const int   oi = __shfl_down(idx, off);
      const float om = __shfl_down(lm, off);
      if (ov > lv || (ov == lv && oi < idx)) { lv = ov; idx = oi; }
      lm = fmaxf(lm, om);
    }
    if ((t & 63) == 0) { redv[t >> 6] = lv; redi[t >> 6] = idx; redm[t >> 6] = lm; }
    __syncthreads();
    if (t == 0) {
      float bv = redv[0]; int bi = redi[0]; float bm = redm[0];
#pragma unroll
      for (int w = 1; w < 5; ++w) {
        if (redv[w] > bv || (redv[w] == bv && redi[w] < bi)) { bv = redv[w]; bi = redi[w]; }
        bm = fmaxf(bm, redm[w]);
      }
      raws = bi; ms = bm;
    }
    __syncthreads();

    // ---- P3: softmax denominator + prob of sampled class ----
    float e = 0.f;
    if (t < CLS && !msk) e = expf(li - ms);
    if (t == raws) praws = e;
    float se = e;
#pragma unroll
    for (int off = 32; off > 0; off >>= 1) se += __shfl_down(se, off);
    if ((t & 63) == 0) reds[t >> 6] = se;
    __syncthreads();
    if (t == 0) {
      const float S = reds[0] + reds[1] + reds[2] + reds[3] + reds[4];
      const float p = praws / S;
      logps = (logps + logf(p + 1e-8f)) - logf(1e-8f);
      const int raw = raws;
      const int chosen = (raw == 256) ? nuseds : raw;
      if (raw == 256) nuseds = nuseds + 1;
      colors[v] = chosen;
    }
    __syncthreads();
  }

  for (int i = t; i < NV; i += 320) out[i] = (float)colors[i];
  if (t == 0) {
    const float nf = (float)nuseds;
    out[NV] = ((nf - baseline[0]) * logps) / 8192.0f;
  }
}

// ---------------------------------------------------------------------------
extern "C" void kernel_launch(void* const* d_in, const int* in_sizes, int n_in,
                              void* d_out, int out_size, void* d_ws, size_t ws_size,
                              hipStream_t stream) {
  const float* emb      = (const float*)d_in[0];
  const int*   nbr      = (const int*)d_in[1];
  const float* W1       = (const float*)d_in[2];
  const float* b1       = (const float*)d_in[3];
  const float* W2       = (const float*)d_in[4];
  const float* b2       = (const float*)d_in[5];
  const float* W3       = (const float*)d_in[6];
  const float* b3       = (const float*)d_in[7];
  const float* baseline = (const float*)d_in[8];
  float* out = (float*)d_out;

  char* ws = (char*)d_ws;
  float* g      = (float*)ws;                                  // 512 f32
  float* part   = (float*)(ws + 2048);                         // 64*512 f32
  float* logits = (float*)(ws + 2048 + 64 * EMB * 4);          // 8192*257 f32

  colmean_part<<<64, 256, 0, stream>>>(emb, part);
  colmean_fin<<<1, 256, 0, stream>>>(part, g);
  mlp3<<<NV / TV, 256, 0, stream>>>(emb, g, W1, b1, W2, b2, W3, b3, logits);
  scan_kernel<<<1, 320, 0, stream>>>(nbr, logits, baseline, out);
}

// Round 2
// 11306.371 us; speedup vs baseline: 1.8120x; 1.8120x over previous
//
#include <hip/hip_runtime.h>
#include <stdint.h>
#include <math.h>

#define NV 8192
#define EMB 512
#define CLS 257
#define DEG 32
#define TV 16
#define NEGINF (-INFINITY)

// ---------------------------------------------------------------------------
// Threefry-2x32, 20 rounds — exactly JAX's _threefry2x32. constexpr so the
// input-independent key chain (seed 42) can be baked in at compile time.
// ---------------------------------------------------------------------------
struct KP { uint32_t a, b; };

__host__ __device__ constexpr KP tfc(uint32_t k0, uint32_t k1,
                                     uint32_t x0, uint32_t x1) {
  const uint32_t ks2 = k0 ^ k1 ^ 0x1BD11BDAu;
  uint32_t v0 = x0 + k0, v1 = x1 + k1;
#define QR(r) { v0 += v1; v1 = (v1 << (r)) | (v1 >> (32 - (r))); v1 ^= v0; }
  QR(13) QR(15) QR(26) QR(6)
  v0 += k1;  v1 += ks2 + 1u;
  QR(17) QR(29) QR(16) QR(24)
  v0 += ks2; v1 += k0 + 2u;
  QR(13) QR(15) QR(26) QR(6)
  v0 += k0;  v1 += k1 + 3u;
  QR(17) QR(29) QR(16) QR(24)
  v0 += k1;  v1 += ks2 + 4u;
  QR(13) QR(15) QR(26) QR(6)
  v0 += ks2; v1 += k0 + 5u;
#undef QR
  return KP{v0, v1};
}

// Key chain: key_state[1] = (0,42); key_state[v+1] = tf(key_state[v], (0,0)).
// Built in 32 constexpr segments (each ~40k constexpr steps, well under limit).
struct Seg { KP e[256]; };
constexpr Seg mkseg(KP s) {
  Seg g{};
  g.e[0] = s;
  for (int i = 1; i < 256; ++i) g.e[i] = tfc(g.e[i - 1].a, g.e[i - 1].b, 0u, 0u);
  return g;
}
#define NXTSEG(prev) mkseg(tfc(prev.e[255].a, prev.e[255].b, 0u, 0u))
constexpr Seg SG0 = mkseg(KP{0u, 42u});
constexpr Seg SG1 = NXTSEG(SG0);   constexpr Seg SG2 = NXTSEG(SG1);
constexpr Seg SG3 = NXTSEG(SG2);   constexpr Seg SG4 = NXTSEG(SG3);
constexpr Seg SG5 = NXTSEG(SG4);   constexpr Seg SG6 = NXTSEG(SG5);
constexpr Seg SG7 = NXTSEG(SG6);   constexpr Seg SG8 = NXTSEG(SG7);
constexpr Seg SG9 = NXTSEG(SG8);   constexpr Seg SG10 = NXTSEG(SG9);
constexpr Seg SG11 = NXTSEG(SG10); constexpr Seg SG12 = NXTSEG(SG11);
constexpr Seg SG13 = NXTSEG(SG12); constexpr Seg SG14 = NXTSEG(SG13);
constexpr Seg SG15 = NXTSEG(SG14); constexpr Seg SG16 = NXTSEG(SG15);
constexpr Seg SG17 = NXTSEG(SG16); constexpr Seg SG18 = NXTSEG(SG17);
constexpr Seg SG19 = NXTSEG(SG18); constexpr Seg SG20 = NXTSEG(SG19);
constexpr Seg SG21 = NXTSEG(SG20); constexpr Seg SG22 = NXTSEG(SG21);
constexpr Seg SG23 = NXTSEG(SG22); constexpr Seg SG24 = NXTSEG(SG23);
constexpr Seg SG25 = NXTSEG(SG24); constexpr Seg SG26 = NXTSEG(SG25);
constexpr Seg SG27 = NXTSEG(SG26); constexpr Seg SG28 = NXTSEG(SG27);
constexpr Seg SG29 = NXTSEG(SG28); constexpr Seg SG30 = NXTSEG(SG29);
constexpr Seg SG31 = NXTSEG(SG30);

struct KT { uint32_t hi[8192]; uint32_t lo[8192]; };
constexpr KT mkkt() {
  KT t{};
  const Seg* sg[32] = {
    &SG0,  &SG1,  &SG2,  &SG3,  &SG4,  &SG5,  &SG6,  &SG7,
    &SG8,  &SG9,  &SG10, &SG11, &SG12, &SG13, &SG14, &SG15,
    &SG16, &SG17, &SG18, &SG19, &SG20, &SG21, &SG22, &SG23,
    &SG24, &SG25, &SG26, &SG27, &SG28, &SG29, &SG30, &SG31 };
  for (int s = 0; s < 32; ++s)
    for (int i = 0; i < 256; ++i) {
      const int v = 1 + s * 256 + i;
      if (v < 8192) { t.hi[v] = sg[s]->e[i].a; t.lo[v] = sg[s]->e[i].b; }
    }
  return t;
}
__device__ const KT KEYS = mkkt();

// ---------------------------------------------------------------------------
// K1: graph_emb = mean(embeddings, axis=0), deterministic two-pass reduction
// ---------------------------------------------------------------------------
__global__ __launch_bounds__(256) void colmean_part(const float* __restrict__ emb,
                                                    float* __restrict__ part) {
  const int b = blockIdx.x;
  const int t = threadIdx.x;
  for (int j = t; j < EMB; j += 256) {
    float s = 0.f;
    const int r0 = b * 128;
    for (int r = 0; r < 128; ++r) s += emb[(size_t)(r0 + r) * EMB + j];
    part[(size_t)b * EMB + j] = s;
  }
}

__global__ __launch_bounds__(256) void colmean_fin(const float* __restrict__ part,
                                                   float* __restrict__ g) {
  const int t = threadIdx.x;
  for (int j = t; j < EMB; j += 256) {
    float s = 0.f;
    for (int b = 0; b < 64; ++b) s += part[(size_t)b * EMB + j];
    g[j] = s / 8192.0f;
  }
}

// ---------------------------------------------------------------------------
// K2: fused 3-layer MLP (layer math bit-identical to the passing round-1
// kernel) + gumbel epilogue: writes raw logits lr[] and perturbed pl[].
// ---------------------------------------------------------------------------
__global__ __launch_bounds__(256) void mlp3g(
    const float* __restrict__ emb, const float* __restrict__ g,
    const float* __restrict__ W1, const float* __restrict__ b1,
    const float* __restrict__ W2, const float* __restrict__ b2,
    const float* __restrict__ W3, const float* __restrict__ b3,
    float* __restrict__ lr, float* __restrict__ pl)
{
  __shared__ float xs[TV][68];
  __shared__ float gs[EMB];
  __shared__ float h1s[TV][EMB];
  __shared__ float h2s[TV][400];

  const int t  = threadIdx.x;
  const int tx = t & 63;
  const int ty = t >> 6;
  const int v0 = blockIdx.x * TV;

  for (int j = t; j < EMB; j += 256) gs[j] = g[j];

  float acc[4][8];
#pragma unroll
  for (int a = 0; a < 4; ++a)
#pragma unroll
    for (int b = 0; b < 8; ++b) acc[a][b] = 0.f;

  for (int kc = 0; kc < 8; ++kc) {
    __syncthreads();
    {
      const int vv = t >> 4;
      const int kk = (t & 15) << 2;
      const float4 s4 = *reinterpret_cast<const float4*>(
          &emb[(size_t)(v0 + vv) * EMB + kc * 64 + kk]);
      xs[vv][kk] = s4.x; xs[vv][kk + 1] = s4.y;
      xs[vv][kk + 2] = s4.z; xs[vv][kk + 3] = s4.w;
    }
    __syncthreads();
    float cacc[4][8];
#pragma unroll
    for (int a = 0; a < 4; ++a)
#pragma unroll
      for (int b = 0; b < 8; ++b) cacc[a][b] = 0.f;
    for (int kk = 0; kk < 64; ++kk) {
      const int k = kc * 64 + kk;
      float w[8];
#pragma unroll
      for (int jj = 0; jj < 8; ++jj) w[jj] = W1[(size_t)k * EMB + tx + 64 * jj];
      float xv[4];
#pragma unroll
      for (int vv = 0; vv < 4; ++vv) xv[vv] = xs[ty * 4 + vv][kk];
#pragma unroll
      for (int vv = 0; vv < 4; ++vv)
#pragma unroll
        for (int jj = 0; jj < 8; ++jj)
          cacc[vv][jj] = fmaf(xv[vv], w[jj], cacc[vv][jj]);
    }
#pragma unroll
    for (int a = 0; a < 4; ++a)
#pragma unroll
      for (int b = 0; b < 8; ++b) acc[a][b] += cacc[a][b];
  }

  float gacc[8];
#pragma unroll
  for (int b = 0; b < 8; ++b) gacc[b] = 0.f;
  for (int kc = 0; kc < 8; ++kc) {
    float cg[8];
#pragma unroll
    for (int b = 0; b < 8; ++b) cg[b] = 0.f;
    for (int kk = 0; kk < 64; ++kk) {
      const int k = kc * 64 + kk;
      const float gv = gs[k];
#pragma unroll
      for (int jj = 0; jj < 8; ++jj)
        cg[jj] = fmaf(gv, W1[(size_t)(EMB + k) * EMB + tx + 64 * jj], cg[jj]);
    }
#pragma unroll
    for (int b = 0; b < 8; ++b) gacc[b] += cg[b];
  }

#pragma unroll
  for (int jj = 0; jj < 8; ++jj) {
    const int j = tx + 64 * jj;
    const float bj = b1[j];
#pragma unroll
    for (int vv = 0; vv < 4; ++vv) {
      float h = (acc[vv][jj] + gacc[jj]) + bj;
      h = (h >= 0.f) ? h : 0.01f * h;
      h1s[ty * 4 + vv][j] = h;
    }
  }
  __syncthreads();

  const int j2a = t;
  const int j2b = t + 256;
  float a2[TV], a2b[TV];
#pragma unroll
  for (int vv = 0; vv < TV; ++vv) { a2[vv] = 0.f; a2b[vv] = 0.f; }
  for (int kc = 0; kc < 8; ++kc) {
    float c2[TV], c2b[TV];
#pragma unroll
    for (int vv = 0; vv < TV; ++vv) { c2[vv] = 0.f; c2b[vv] = 0.f; }
    for (int kk = 0; kk < 64; ++kk) {
      const int k = kc * 64 + kk;
      const float w0  = W2[(size_t)k * 400 + j2a];
      const float w1v = (j2b < 400) ? W2[(size_t)k * 400 + j2b] : 0.f;
#pragma unroll
      for (int vv = 0; vv < TV; ++vv) {
        const float hv = h1s[vv][k];
        c2[vv]  = fmaf(hv, w0,  c2[vv]);
        c2b[vv] = fmaf(hv, w1v, c2b[vv]);
      }
    }
#pragma unroll
    for (int vv = 0; vv < TV; ++vv) { a2[vv] += c2[vv]; a2b[vv] += c2b[vv]; }
  }
  {
    const float bja = b2[j2a];
#pragma unroll
    for (int vv = 0; vv < TV; ++vv) {
      float h = a2[vv] + bja;
      h2s[vv][j2a] = (h >= 0.f) ? h : 0.01f * h;
    }
    if (j2b < 400) {
      const float bjb = b2[j2b];
#pragma unroll
      for (int vv = 0; vv < TV; ++vv) {
        float h = a2b[vv] + bjb;
        h2s[vv][j2b] = (h >= 0.f) ? h : 0.01f * h;
      }
    }
  }
  __syncthreads();

  float a3[TV], a3x[TV];
#pragma unroll
  for (int vv = 0; vv < TV; ++vv) { a3[vv] = 0.f; a3x[vv] = 0.f; }
  for (int kc = 0; kc < 8; ++kc) {
    float c3[TV], c3x[TV];
#pragma unroll
    for (int vv = 0; vv < TV; ++vv) { c3[vv] = 0.f; c3x[vv] = 0.f; }
    for (int kk = 0; kk < 50; ++kk) {
      const int k = kc * 50 + kk;
      const float w0 = W3[(size_t)k * CLS + t];
      const float wx = (t == 0) ? W3[(size_t)k * CLS + 256] : 0.f;
#pragma unroll
      for (int vv = 0; vv < TV; ++vv) {
        const float hv = h2s[vv][k];
        c3[vv]  = fmaf(hv, w0, c3[vv]);
        c3x[vv] = fmaf(hv, wx, c3x[vv]);
      }
    }
#pragma unroll
    for (int vv = 0; vv < TV; ++vv) { a3[vv] += c3[vv]; a3x[vv] += c3x[vv]; }
  }

  // ---- epilogue: logits + gumbel (identical float pipeline to round 1) ----
  {
    const float bj = b3[t];
#pragma unroll
    for (int vv = 0; vv < TV; ++vv) {
      const int v = v0 + vv;
      const float li = a3[vv] + bj;
      const KP sk = tfc(KEYS.hi[v], KEYS.lo[v], 0u, 1u);
      const KP o  = tfc(sk.a, sk.b, 0u, (uint32_t)t);
      const uint32_t bb = o.a ^ o.b;
      const float f = __uint_as_float(0x3f800000u | (bb >> 9)) - 1.0f;
      const float u = fmaxf(1.17549435e-38f, f);
      const float gg = -logf(-logf(u));
      lr[(size_t)v * CLS + t] = li;
      pl[(size_t)v * CLS + t] = li + gg;
    }
    if (t == 0) {
      const float bx = b3[256];
#pragma unroll
      for (int vv = 0; vv < TV; ++vv) {
        const int v = v0 + vv;
        const float li = a3x[vv] + bx;
        const KP sk = tfc(KEYS.hi[v], KEYS.lo[v], 0u, 1u);
        const KP o  = tfc(sk.a, sk.b, 0u, 256u);
        const uint32_t bb = o.a ^ o.b;
        const float f = __uint_as_float(0x3f800000u | (bb >> 9)) - 1.0f;
        const float u = fmaxf(1.17549435e-38f, f);
        const float gg = -logf(-logf(u));
        lr[(size_t)v * CLS + 256] = li;
        pl[(size_t)v * CLS + 256] = li + gg;
      }
    }
  }
}

// ---------------------------------------------------------------------------
// K3: single-wave sequential scan. Zero barriers; DPP butterflies; stale
// neighbor gather with register fix; double-buffered banned masks; 1-deep
// global prefetch of pl/lr rows.
// ---------------------------------------------------------------------------
#define DPPF(CTRL, OLDI, X) \
  __builtin_amdgcn_update_dpp((int)(OLDI), (X), (CTRL), 0xF, 0xF, false)

#define ARED(CTRL) {                                                          \
  const float ov = __int_as_float(DPPF(CTRL, 0xFF800000u, __float_as_int(bv)));\
  const int   oi = DPPF(CTRL, 0x7FFFFFFF, bi);                                \
  const float om = __int_as_float(DPPF(CTRL, 0xFF800000u, __float_as_int(mvv)));\
  const bool tk = (ov > bv) || (ov == bv && oi < bi);                         \
  bv = tk ? ov : bv; bi = tk ? oi : bi;                                       \
  mvv = fmaxf(mvv, om); }

#define SRED(CTRL) { S += __int_as_float(DPPF(CTRL, 0, __float_as_int(S))); }

__global__ __launch_bounds__(64) void scan2(
    const int* __restrict__ nbr, const float* __restrict__ pl,
    const float* __restrict__ lr, const float* __restrict__ baseline,
    float* __restrict__ out)
{
  __shared__ int colors[NV];          // 32 KB
  __shared__ unsigned bbuf[2][16];    // double-buffered 288-bit ban masks

  const int lane = threadIdx.x;
  const int ln32 = lane & 31;

  for (int i = lane; i < NV; i += 64) colors[i] = -1;
  if (lane == 0) colors[0] = 0;

  // ---- prologue: build state for v = 1 ----
  int nbrv = nbr[DEG + ln32];
  int nbrn = nbr[2 * DEG + ln32];
  bbuf[1][lane & 15] = 0u;
  {
    const int cg0 = colors[nbrv];
    if (cg0 >= 0) atomicOr(&bbuf[1][cg0 >> 5], 1u << (cg0 & 31));
  }
  unsigned bw[4];
#pragma unroll
  for (int j = 0; j < 4; ++j) bw[j] = bbuf[1][(lane >> 5) + 2 * j];
  unsigned bw8 = bbuf[1][8];

  float plc[5], lrc[5];
  {
    const size_t o = (size_t)CLS + lane;
#pragma unroll
    for (int j = 0; j < 4; ++j) { plc[j] = pl[o + 64 * j]; lrc[j] = lr[o + 64 * j]; }
    plc[4] = pl[CLS + 256]; lrc[4] = lr[CLS + 256];
  }

  int chosen_prev = 0;
  int n_used = 1;
  float logp = 0.f;

  for (int v = 1; v < NV; ++v) {
    const int vp1 = (v + 1 < NV) ? v + 1 : NV - 1;
    const int vp2 = (v + 2 < NV) ? v + 2 : NV - 1;

    // prefetch next-row logits + neighbor indices (consumed next iter)
    float pln[5], lrn[5];
    {
      const size_t o = (size_t)vp1 * CLS + lane;
#pragma unroll
      for (int j = 0; j < 4; ++j) { pln[j] = pl[o + 64 * j]; lrn[j] = lr[o + 64 * j]; }
      pln[4] = pl[(size_t)vp1 * CLS + 256];
      lrn[4] = lr[(size_t)vp1 * CLS + 256];
    }
    const int nbrn2 = nbr[(size_t)vp2 * DEG + ln32];

    const int nb = (v + 1) & 1;
    bbuf[nb][lane & 15] = 0u;          // zero next ban buffer
    const int cgn = colors[nbrn];      // stale gather for v+1 (misses only v)

    // ---- mask for v (register fix covers neighbor == v-1) ----
    const bool has_fix = (__ballot(nbrv == (v - 1)) != 0ULL);
    const int fixc = chosen_prev;
    bool mk[4];
#pragma unroll
    for (int j = 0; j < 4; ++j) {
      const int c = lane + 64 * j;
      mk[j] = (((bw[j] >> ln32) & 1u) != 0u)
           || (has_fix && c == fixc)
           || (c >= n_used && c < 256);
    }
    const bool mk4 = ((bw8 & 1u) != 0u) || (has_fix && fixc == 256);

    // ---- local fold (first-index tie-break), slot4 = class 256 ----
    float bv = mk[0] ? NEGINF : plc[0];
    int   bi = mk[0] ? 0x7FFFFFFF : lane;
    float mvv = mk[0] ? NEGINF : lrc[0];
#pragma unroll
    for (int j = 1; j < 4; ++j) {
      const float vj = mk[j] ? NEGINF : plc[j];
      const int   ij = mk[j] ? 0x7FFFFFFF : lane + 64 * j;
      const bool tk = (vj > bv) || (vj == bv && ij < bi);
      bv = tk ? vj : bv; bi = tk ? ij : bi;
      mvv = fmaxf(mvv, mk[j] ? NEGINF : lrc[j]);
    }
    {
      const float v4 = mk4 ? NEGINF : plc[4];
      const int   i4 = mk4 ? 0x7FFFFFFF : 256;
      const bool tk = (v4 > bv) || (v4 == bv && i4 < bi);
      bv = tk ? v4 : bv; bi = tk ? i4 : bi;
      mvv = fmaxf(mvv, mk4 ? NEGINF : lrc[4]);
    }

    // ban scatter for v+1 (latency hides under DPP phase)
    if (cgn >= 0) atomicOr(&bbuf[nb][cgn >> 5], 1u << (cgn & 31));

    // ---- DPP argmax(perturbed) + max(raw, masked) -> lane 63 ----
    ARED(0x111) ARED(0x112) ARED(0x114) ARED(0x118) ARED(0x142) ARED(0x143)
    const int raw = __builtin_amdgcn_readlane(bi, 63);
    const float m = __int_as_float(__builtin_amdgcn_readlane(__float_as_int(mvv), 63));

    // banned word reads for v+1 (after scatter; same-wave LDS is in-order)
    unsigned bwn[4];
#pragma unroll
    for (int j = 0; j < 4; ++j) bwn[j] = bbuf[nb][(lane >> 5) + 2 * j];
    const unsigned bwn8 = bbuf[nb][8];

    // ---- softmax prob of sampled class ----
    const float e0 = mk[0] ? 0.f : expf(lrc[0] - m);
    const float e1 = mk[1] ? 0.f : expf(lrc[1] - m);
    const float e2 = mk[2] ? 0.f : expf(lrc[2] - m);
    const float e3 = mk[3] ? 0.f : expf(lrc[3] - m);
    const float e4 = (!mk4 && lane == 0) ? expf(lrc[4] - m) : 0.f;
    float S = ((e0 + e1) + (e2 + e3)) + e4;
    SRED(0x111) SRED(0x112) SRED(0x114) SRED(0x118) SRED(0x142) SRED(0x143)
    const float Sall = __int_as_float(__builtin_amdgcn_readlane(__float_as_int(S), 63));

    const bool isnew = (raw == 256);
    const int jsel  = isnew ? 4 : (raw >> 6);
    const int owner = isnew ? 0 : (raw & 63);
    const float cand = (jsel == 0) ? e0 : (jsel == 1) ? e1 : (jsel == 2) ? e2
                      : (jsel == 3) ? e3 : e4;
    const float praw = __int_as_float(
        __builtin_amdgcn_readlane(__float_as_int(cand), owner));

    const float p = praw / Sall;
    logp = (logp + logf(p + 1e-8f)) - logf(1e-8f);

    const int chosen = isnew ? n_used : raw;
    if (isnew) ++n_used;
    if (lane == 0) colors[v] = chosen;

    // ---- shift pipelined state ----
#pragma unroll
    for (int j = 0; j < 4; ++j) { plc[j] = pln[j]; lrc[j] = lrn[j]; bw[j] = bwn[j]; }
    plc[4] = pln[4]; lrc[4] = lrn[4]; bw8 = bwn8;
    nbrv = nbrn; nbrn = nbrn2; chosen_prev = chosen;
  }

  for (int i = lane; i < NV; i += 64) out[i] = (float)colors[i];
  if (lane == 0)
    out[NV] = (((float)n_used) - baseline[0]) * logp / 8192.0f;
}

// ---------------------------------------------------------------------------
extern "C" void kernel_launch(void* const* d_in, const int* in_sizes, int n_in,
                              void* d_out, int out_size, void* d_ws, size_t ws_size,
                              hipStream_t stream) {
  const float* emb      = (const float*)d_in[0];
  const int*   nbr      = (const int*)d_in[1];
  const float* W1       = (const float*)d_in[2];
  const float* b1       = (const float*)d_in[3];
  const float* W2       = (const float*)d_in[4];
  const float* b2       = (const float*)d_in[5];
  const float* W3       = (const float*)d_in[6];
  const float* b3       = (const float*)d_in[7];
  const float* baseline = (const float*)d_in[8];
  float* out = (float*)d_out;

  char* ws = (char*)d_ws;
  float* g     = (float*)ws;                                     // 2 KB
  float* part  = (float*)(ws + 2048);                            // 128 KB
  float* lrbuf = (float*)(ws + 2048 + 131072);                   // 8.42 MB
  float* plbuf = (float*)(ws + 2048 + 131072 + 8421376);         // 8.42 MB

  colmean_part<<<64, 256, 0, stream>>>(emb, part);
  colmean_fin<<<1, 256, 0, stream>>>(part, g);
  mlp3g<<<NV / TV, 256, 0, stream>>>(emb, g, W1, b1, W2, b2, W3, b3, lrbuf, plbuf);
  scan2<<<1, 64, 0, stream>>>(nbr, plbuf, lrbuf, baseline, out);
}

// Round 3
// 8158.424 us; speedup vs baseline: 2.5111x; 1.3859x over previous
//
#include <hip/hip_runtime.h>
#include <stdint.h>
#include <math.h>

#define NV 8192
#define EMB 512
#define CLS 257
#define DEG 32
#define TV 16
#define RSTRIDE 260   // padded row stride (multiple of 4 floats -> 16B aligned)
#define NEGINF (-INFINITY)

// ---------------------------------------------------------------------------
// Threefry-2x32, 20 rounds — exactly JAX's _threefry2x32. constexpr so the
// input-independent key chain (seed 42) can be baked in at compile time.
// ---------------------------------------------------------------------------
struct KP { uint32_t a, b; };

__host__ __device__ constexpr KP tfc(uint32_t k0, uint32_t k1,
                                     uint32_t x0, uint32_t x1) {
  const uint32_t ks2 = k0 ^ k1 ^ 0x1BD11BDAu;
  uint32_t v0 = x0 + k0, v1 = x1 + k1;
#define QR(r) { v0 += v1; v1 = (v1 << (r)) | (v1 >> (32 - (r))); v1 ^= v0; }
  QR(13) QR(15) QR(26) QR(6)
  v0 += k1;  v1 += ks2 + 1u;
  QR(17) QR(29) QR(16) QR(24)
  v0 += ks2; v1 += k0 + 2u;
  QR(13) QR(15) QR(26) QR(6)
  v0 += k0;  v1 += k1 + 3u;
  QR(17) QR(29) QR(16) QR(24)
  v0 += k1;  v1 += ks2 + 4u;
  QR(13) QR(15) QR(26) QR(6)
  v0 += ks2; v1 += k0 + 5u;
#undef QR
  return KP{v0, v1};
}

struct Seg { KP e[256]; };
constexpr Seg mkseg(KP s) {
  Seg g{};
  g.e[0] = s;
  for (int i = 1; i < 256; ++i) g.e[i] = tfc(g.e[i - 1].a, g.e[i - 1].b, 0u, 0u);
  return g;
}
#define NXTSEG(prev) mkseg(tfc(prev.e[255].a, prev.e[255].b, 0u, 0u))
constexpr Seg SG0 = mkseg(KP{0u, 42u});
constexpr Seg SG1 = NXTSEG(SG0);   constexpr Seg SG2 = NXTSEG(SG1);
constexpr Seg SG3 = NXTSEG(SG2);   constexpr Seg SG4 = NXTSEG(SG3);
constexpr Seg SG5 = NXTSEG(SG4);   constexpr Seg SG6 = NXTSEG(SG5);
constexpr Seg SG7 = NXTSEG(SG6);   constexpr Seg SG8 = NXTSEG(SG7);
constexpr Seg SG9 = NXTSEG(SG8);   constexpr Seg SG10 = NXTSEG(SG9);
constexpr Seg SG11 = NXTSEG(SG10); constexpr Seg SG12 = NXTSEG(SG11);
constexpr Seg SG13 = NXTSEG(SG12); constexpr Seg SG14 = NXTSEG(SG13);
constexpr Seg SG15 = NXTSEG(SG14); constexpr Seg SG16 = NXTSEG(SG15);
constexpr Seg SG17 = NXTSEG(SG16); constexpr Seg SG18 = NXTSEG(SG17);
constexpr Seg SG19 = NXTSEG(SG18); constexpr Seg SG20 = NXTSEG(SG19);
constexpr Seg SG21 = NXTSEG(SG20); constexpr Seg SG22 = NXTSEG(SG21);
constexpr Seg SG23 = NXTSEG(SG22); constexpr Seg SG24 = NXTSEG(SG23);
constexpr Seg SG25 = NXTSEG(SG24); constexpr Seg SG26 = NXTSEG(SG25);
constexpr Seg SG27 = NXTSEG(SG26); constexpr Seg SG28 = NXTSEG(SG27);
constexpr Seg SG29 = NXTSEG(SG28); constexpr Seg SG30 = NXTSEG(SG29);
constexpr Seg SG31 = NXTSEG(SG30);

struct KT { uint32_t hi[8192]; uint32_t lo[8192]; };
constexpr KT mkkt() {
  KT t{};
  const Seg* sg[32] = {
    &SG0,  &SG1,  &SG2,  &SG3,  &SG4,  &SG5,  &SG6,  &SG7,
    &SG8,  &SG9,  &SG10, &SG11, &SG12, &SG13, &SG14, &SG15,
    &SG16, &SG17, &SG18, &SG19, &SG20, &SG21, &SG22, &SG23,
    &SG24, &SG25, &SG26, &SG27, &SG28, &SG29, &SG30, &SG31 };
  for (int s = 0; s < 32; ++s)
    for (int i = 0; i < 256; ++i) {
      const int v = 1 + s * 256 + i;
      if (v < 8192) { t.hi[v] = sg[s]->e[i].a; t.lo[v] = sg[s]->e[i].b; }
    }
  return t;
}
__device__ const KT KEYS = mkkt();

// ---------------------------------------------------------------------------
// K1: graph_emb = mean(embeddings, axis=0), deterministic two-pass reduction
// ---------------------------------------------------------------------------
__global__ __launch_bounds__(256) void colmean_part(const float* __restrict__ emb,
                                                    float* __restrict__ part) {
  const int b = blockIdx.x;
  const int t = threadIdx.x;
  for (int j = t; j < EMB; j += 256) {
    float s = 0.f;
    const int r0 = b * 128;
    for (int r = 0; r < 128; ++r) s += emb[(size_t)(r0 + r) * EMB + j];
    part[(size_t)b * EMB + j] = s;
  }
}

__global__ __launch_bounds__(256) void colmean_fin(const float* __restrict__ part,
                                                   float* __restrict__ g) {
  const int t = threadIdx.x;
  for (int j = t; j < EMB; j += 256) {
    float s = 0.f;
    for (int b = 0; b < 64; ++b) s += part[(size_t)b * EMB + j];
    g[j] = s / 8192.0f;
  }
}

// ---------------------------------------------------------------------------
// K2: fused 3-layer MLP (layer math bit-identical to the passing round-2
// kernel) + epilogue: perturbed logits pl[] and er[] = exp(li - rowmax).
// ---------------------------------------------------------------------------
__global__ __launch_bounds__(256) void mlp3g(
    const float* __restrict__ emb, const float* __restrict__ g,
    const float* __restrict__ W1, const float* __restrict__ b1,
    const float* __restrict__ W2, const float* __restrict__ b2,
    const float* __restrict__ W3, const float* __restrict__ b3,
    float* __restrict__ pl, float* __restrict__ er)
{
  __shared__ float xs[TV][68];
  __shared__ float gs[EMB];
  __shared__ float h1s[TV][EMB];
  __shared__ float h2s[TV][400];
  __shared__ float redw[TV][4];
  __shared__ float li256s[TV];
  __shared__ float mrs[TV];

  const int t  = threadIdx.x;
  const int tx = t & 63;
  const int ty = t >> 6;
  const int v0 = blockIdx.x * TV;

  for (int j = t; j < EMB; j += 256) gs[j] = g[j];

  float acc[4][8];
#pragma unroll
  for (int a = 0; a < 4; ++a)
#pragma unroll
    for (int b = 0; b < 8; ++b) acc[a][b] = 0.f;

  for (int kc = 0; kc < 8; ++kc) {
    __syncthreads();
    {
      const int vv = t >> 4;
      const int kk = (t & 15) << 2;
      const float4 s4 = *reinterpret_cast<const float4*>(
          &emb[(size_t)(v0 + vv) * EMB + kc * 64 + kk]);
      xs[vv][kk] = s4.x; xs[vv][kk + 1] = s4.y;
      xs[vv][kk + 2] = s4.z; xs[vv][kk + 3] = s4.w;
    }
    __syncthreads();
    float cacc[4][8];
#pragma unroll
    for (int a = 0; a < 4; ++a)
#pragma unroll
      for (int b = 0; b < 8; ++b) cacc[a][b] = 0.f;
    for (int kk = 0; kk < 64; ++kk) {
      const int k = kc * 64 + kk;
      float w[8];
#pragma unroll
      for (int jj = 0; jj < 8; ++jj) w[jj] = W1[(size_t)k * EMB + tx + 64 * jj];
      float xv[4];
#pragma unroll
      for (int vv = 0; vv < 4; ++vv) xv[vv] = xs[ty * 4 + vv][kk];
#pragma unroll
      for (int vv = 0; vv < 4; ++vv)
#pragma unroll
        for (int jj = 0; jj < 8; ++jj)
          cacc[vv][jj] = fmaf(xv[vv], w[jj], cacc[vv][jj]);
    }
#pragma unroll
    for (int a = 0; a < 4; ++a)
#pragma unroll
      for (int b = 0; b < 8; ++b) acc[a][b] += cacc[a][b];
  }

  float gacc[8];
#pragma unroll
  for (int b = 0; b < 8; ++b) gacc[b] = 0.f;
  for (int kc = 0; kc < 8; ++kc) {
    float cg[8];
#pragma unroll
    for (int b = 0; b < 8; ++b) cg[b] = 0.f;
    for (int kk = 0; kk < 64; ++kk) {
      const int k = kc * 64 + kk;
      const float gv = gs[k];
#pragma unroll
      for (int jj = 0; jj < 8; ++jj)
        cg[jj] = fmaf(gv, W1[(size_t)(EMB + k) * EMB + tx + 64 * jj], cg[jj]);
    }
#pragma unroll
    for (int b = 0; b < 8; ++b) gacc[b] += cg[b];
  }

#pragma unroll
  for (int jj = 0; jj < 8; ++jj) {
    const int j = tx + 64 * jj;
    const float bj = b1[j];
#pragma unroll
    for (int vv = 0; vv < 4; ++vv) {
      float h = (acc[vv][jj] + gacc[jj]) + bj;
      h = (h >= 0.f) ? h : 0.01f * h;
      h1s[ty * 4 + vv][j] = h;
    }
  }
  __syncthreads();

  const int j2a = t;
  const int j2b = t + 256;
  float a2[TV], a2b[TV];
#pragma unroll
  for (int vv = 0; vv < TV; ++vv) { a2[vv] = 0.f; a2b[vv] = 0.f; }
  for (int kc = 0; kc < 8; ++kc) {
    float c2[TV], c2b[TV];
#pragma unroll
    for (int vv = 0; vv < TV; ++vv) { c2[vv] = 0.f; c2b[vv] = 0.f; }
    for (int kk = 0; kk < 64; ++kk) {
      const int k = kc * 64 + kk;
      const float w0  = W2[(size_t)k * 400 + j2a];
      const float w1v = (j2b < 400) ? W2[(size_t)k * 400 + j2b] : 0.f;
#pragma unroll
      for (int vv = 0; vv < TV; ++vv) {
        const float hv = h1s[vv][k];
        c2[vv]  = fmaf(hv, w0,  c2[vv]);
        c2b[vv] = fmaf(hv, w1v, c2b[vv]);
      }
    }
#pragma unroll
    for (int vv = 0; vv < TV; ++vv) { a2[vv] += c2[vv]; a2b[vv] += c2b[vv]; }
  }
  {
    const float bja = b2[j2a];
#pragma unroll
    for (int vv = 0; vv < TV; ++vv) {
      float h = a2[vv] + bja;
      h2s[vv][j2a] = (h >= 0.f) ? h : 0.01f * h;
    }
    if (j2b < 400) {
      const float bjb = b2[j2b];
#pragma unroll
      for (int vv = 0; vv < TV; ++vv) {
        float h = a2b[vv] + bjb;
        h2s[vv][j2b] = (h >= 0.f) ? h : 0.01f * h;
      }
    }
  }
  __syncthreads();

  float a3[TV], a3x[TV];
#pragma unroll
  for (int vv = 0; vv < TV; ++vv) { a3[vv] = 0.f; a3x[vv] = 0.f; }
  for (int kc = 0; kc < 8; ++kc) {
    float c3[TV], c3x[TV];
#pragma unroll
    for (int vv = 0; vv < TV; ++vv) { c3[vv] = 0.f; c3x[vv] = 0.f; }
    for (int kk = 0; kk < 50; ++kk) {
      const int k = kc * 50 + kk;
      const float w0 = W3[(size_t)k * CLS + t];
      const float wx = (t == 0) ? W3[(size_t)k * CLS + 256] : 0.f;
#pragma unroll
      for (int vv = 0; vv < TV; ++vv) {
        const float hv = h2s[vv][k];
        c3[vv]  = fmaf(hv, w0, c3[vv]);
        c3x[vv] = fmaf(hv, wx, c3x[vv]);
      }
    }
#pragma unroll
    for (int vv = 0; vv < TV; ++vv) { a3[vv] += c3[vv]; a3x[vv] += c3x[vv]; }
  }

  // ---- epilogue: row max, er = exp(li - mr), pl = li + gumbel (exact) ----
  const float bj = b3[t];
  float li_[TV];
#pragma unroll
  for (int vv = 0; vv < TV; ++vv) li_[vv] = a3[vv] + bj;

#pragma unroll
  for (int vv = 0; vv < TV; ++vv) {
    float m = li_[vv];
#pragma unroll
    for (int off = 1; off < 64; off <<= 1) m = fmaxf(m, __shfl_xor(m, off));
    if ((t & 63) == 0) redw[vv][t >> 6] = m;
  }
  if (t == 0) {
    const float bx = b3[256];
#pragma unroll
    for (int vv = 0; vv < TV; ++vv) li256s[vv] = a3x[vv] + bx;
  }
  __syncthreads();
  if (t < TV) {
    const float m = fmaxf(fmaxf(redw[t][0], redw[t][1]),
                          fmaxf(redw[t][2], redw[t][3]));
    mrs[t] = fmaxf(m, li256s[t]);
  }
  __syncthreads();

#pragma unroll
  for (int vv = 0; vv < TV; ++vv) {
    const int v = v0 + vv;
    const float li = li_[vv];
    const KP sk = tfc(KEYS.hi[v], KEYS.lo[v], 0u, 1u);
    const KP o  = tfc(sk.a, sk.b, 0u, (uint32_t)t);
    const uint32_t bb = o.a ^ o.b;
    const float f = __uint_as_float(0x3f800000u | (bb >> 9)) - 1.0f;
    const float u = fmaxf(1.17549435e-38f, f);
    const float gg = -logf(-logf(u));
    pl[(size_t)v * RSTRIDE + t] = li + gg;
    er[(size_t)v * RSTRIDE + t] = expf(li - mrs[vv]);
  }
  if (t == 0) {
    const float bx = b3[256];
#pragma unroll
    for (int vv = 0; vv < TV; ++vv) {
      const int v = v0 + vv;
      const float li = a3x[vv] + bx;
      const KP sk = tfc(KEYS.hi[v], KEYS.lo[v], 0u, 1u);
      const KP o  = tfc(sk.a, sk.b, 0u, 256u);
      const uint32_t bb = o.a ^ o.b;
      const float f = __uint_as_float(0x3f800000u | (bb >> 9)) - 1.0f;
      const float u = fmaxf(1.17549435e-38f, f);
      const float gg = -logf(-logf(u));
      pl[(size_t)v * RSTRIDE + 256] = li + gg;
      er[(size_t)v * RSTRIDE + 256] = expf(li - mrs[vv]);
    }
  }
}

// ---------------------------------------------------------------------------
// K3: producer-consumer scan. Wave 0 = consumer (sequential sampling),
// wave 1 = producer (streams pl/er rows into a 32-row LDS ring).
// ---------------------------------------------------------------------------
#define DPPF(CTRL, OLDI, X) \
  __builtin_amdgcn_update_dpp((int)(OLDI), (X), (CTRL), 0xF, 0xF, false)

#define ARED(CTRL) {                                                           \
  const float ov = __int_as_float(DPPF(CTRL, 0xFF800000u, __float_as_int(bv)));\
  const int   oi = DPPF(CTRL, 0x7FFFFFFF, bi);                                 \
  const bool tk = (ov > bv) || (ov == bv && oi < bi);                          \
  bv = tk ? ov : bv; bi = tk ? oi : bi; }

#define SRED(CTRL) { S += __int_as_float(DPPF(CTRL, 0, __float_as_int(S))); }

#define WG_SCOPE __HIP_MEMORY_SCOPE_WORKGROUP

__global__ __launch_bounds__(128) void scan3(
    const int* __restrict__ nbr, const float* __restrict__ plG,
    const float* __restrict__ erG, const float* __restrict__ baseline,
    float* __restrict__ out)
{
  __shared__ int colors[NV];          // 32 KB
  __shared__ float plR[32][RSTRIDE];  // 33.3 KB ring
  __shared__ float erR[32][RSTRIDE];  // 33.3 KB ring
  __shared__ unsigned bbuf[2][16];
  __shared__ int prod_done, cons_done;

  const int t = threadIdx.x;
  const int lane = t & 63;
  const int ln32 = lane & 31;

  for (int i = t; i < NV; i += 128) colors[i] = -1;
  if (t == 0) { colors[0] = 0; prod_done = 0; cons_done = 0; }
  __syncthreads();

  if (t >= 64) {
    // ================= producer wave =================
    for (int pc = 0; pc < 1024; ++pc) {
      while (__hip_atomic_load(&cons_done, __ATOMIC_ACQUIRE, WG_SCOPE) < pc - 3) {}
      float4 pbuf[8], ebuf[8];
      float pX[8], eX[8];
#pragma unroll
      for (int r = 0; r < 8; ++r) {
        const int v = pc * 8 + r;
        const size_t base = (size_t)v * RSTRIDE;
        pbuf[r] = *reinterpret_cast<const float4*>(plG + base + 4 * lane);
        ebuf[r] = *reinterpret_cast<const float4*>(erG + base + 4 * lane);
        pX[r] = plG[base + 256];
        eX[r] = erG[base + 256];
      }
#pragma unroll
      for (int r = 0; r < 8; ++r) {
        const int slot = (pc * 8 + r) & 31;
        *reinterpret_cast<float4*>(&plR[slot][4 * lane]) = pbuf[r];
        *reinterpret_cast<float4*>(&erR[slot][4 * lane]) = ebuf[r];
        if (lane == 0) { plR[slot][256] = pX[r]; erR[slot][256] = eX[r]; }
      }
      __hip_atomic_store(&prod_done, pc + 1, __ATOMIC_RELEASE, WG_SCOPE);
    }
    return;
  }

  // ================= consumer wave =================
  while (__hip_atomic_load(&prod_done, __ATOMIC_ACQUIRE, WG_SCOPE) < 1) {}

  // prologue: state for v = 1
  float plc[4], erc[4], plcX, ercX;
#pragma unroll
  for (int j = 0; j < 4; ++j) {
    plc[j] = plR[1][lane + 64 * j];
    erc[j] = erR[1][lane + 64 * j];
  }
  plcX = plR[1][256]; ercX = erR[1][256];

  int nbrv = nbr[DEG + ln32];
  int nbrn = nbr[2 * DEG + ln32];
  bbuf[1][lane & 15] = 0u;
  {
    const int cg0 = colors[nbrv];
    if (cg0 >= 0) atomicOr(&bbuf[1][cg0 >> 5], 1u << (cg0 & 31));
  }
  unsigned bw[4];
#pragma unroll
  for (int j = 0; j < 4; ++j) bw[j] = bbuf[1][(lane >> 5) + 2 * j];
  unsigned bw8 = bbuf[1][8];

  int chosen_prev = 0;
  int n_used = 1;
  float logp = 0.f;

  for (int v = 1; v < NV; ++v) {
    const int vp1 = (v + 1 < NV) ? v + 1 : NV - 1;
    const int vp2 = (v + 2 < NV) ? v + 2 : NV - 1;

    // chunk sync (amortized 1/8 iterations)
    if ((v & 7) == 7) {
      __hip_atomic_store(&cons_done, (v + 1) >> 3, __ATOMIC_RELEASE, WG_SCOPE);
      const int tgt = (vp1 >> 3) + 1;
      while (__hip_atomic_load(&prod_done, __ATOMIC_ACQUIRE, WG_SCOPE) < tgt) {}
    }

    // issue next-row LDS reads (consumed next iteration)
    const int sN = vp1 & 31;
    float pln[4], ern[4];
#pragma unroll
    for (int j = 0; j < 4; ++j) {
      pln[j] = plR[sN][lane + 64 * j];
      ern[j] = erR[sN][lane + 64 * j];
    }
    const float plnX = plR[sN][256];
    const float ernX = erR[sN][256];
    const int nbrn2 = nbr[(size_t)vp2 * DEG + ln32];

    // ban pipeline for v+1
    const int nb = vp1 & 1;
    bbuf[nb][lane & 15] = 0u;
    const int cgn = colors[nbrn];      // stale gather (misses only v)

    // ---- mask for v (register fix covers neighbor == v-1) ----
    const bool has_fix = (__ballot(nbrv == (v - 1)) != 0ULL);
    const int fixc = chosen_prev;
    bool mk[4];
#pragma unroll
    for (int j = 0; j < 4; ++j) {
      const int c = lane + 64 * j;
      mk[j] = (((bw[j] >> ln32) & 1u) != 0u)
           || (has_fix && c == fixc)
           || (c >= n_used && c < 256);
    }
    const bool mk4 = ((bw8 & 1u) != 0u) || (has_fix && fixc == 256);

    // ---- local fold (first-index tie-break), slot4 = class 256 ----
    float bv = mk[0] ? NEGINF : plc[0];
    int   bi = mk[0] ? 0x7FFFFFFF : lane;
#pragma unroll
    for (int j = 1; j < 4; ++j) {
      const float vj = mk[j] ? NEGINF : plc[j];
      const int   ij = mk[j] ? 0x7FFFFFFF : lane + 64 * j;
      const bool tk = (vj > bv) || (vj == bv && ij < bi);
      bv = tk ? vj : bv; bi = tk ? ij : bi;
    }
    {
      const float v4 = mk4 ? NEGINF : plcX;
      const int   i4 = mk4 ? 0x7FFFFFFF : 256;
      const bool tk = (v4 > bv) || (v4 == bv && i4 < bi);
      bv = tk ? v4 : bv; bi = tk ? i4 : bi;
    }

    // ban scatter for v+1 (hides under DPP phase)
    if (cgn >= 0) atomicOr(&bbuf[nb][cgn >> 5], 1u << (cgn & 31));

    // ---- masked softmax denominator (independent of argmax chain) ----
    const float e0 = mk[0] ? 0.f : erc[0];
    const float e1 = mk[1] ? 0.f : erc[1];
    const float e2 = mk[2] ? 0.f : erc[2];
    const float e3 = mk[3] ? 0.f : erc[3];
    const float e4 = (!mk4 && lane == 0) ? ercX : 0.f;
    float S = ((e0 + e1) + (e2 + e3)) + e4;
    SRED(0x111) SRED(0x112) SRED(0x114) SRED(0x118) SRED(0x142) SRED(0x143)

    // ---- DPP argmax(perturbed) -> lane 63 ----
    ARED(0x111) ARED(0x112) ARED(0x114) ARED(0x118) ARED(0x142) ARED(0x143)
    const int raw = __builtin_amdgcn_readlane(bi, 63);
    const float Sall = __int_as_float(
        __builtin_amdgcn_readlane(__float_as_int(S), 63));

    // banned word reads for v+1 (after scatter; same-wave LDS is in-order)
    unsigned bwn[4];
#pragma unroll
    for (int j = 0; j < 4; ++j) bwn[j] = bbuf[nb][(lane >> 5) + 2 * j];
    const unsigned bwn8 = bbuf[nb][8];

    const bool isnew = (raw == 256);
    const int jsel  = isnew ? 4 : (raw >> 6);
    const int owner = isnew ? 0 : (raw & 63);
    const float cand = (jsel == 0) ? erc[0] : (jsel == 1) ? erc[1]
                     : (jsel == 2) ? erc[2] : (jsel == 3) ? erc[3] : ercX;
    const float praw = __int_as_float(
        __builtin_amdgcn_readlane(__float_as_int(cand), owner));

    const float p = praw / Sall;
    logp = (logp + logf(p + 1e-8f)) - logf(1e-8f);

    const int chosen = isnew ? n_used : raw;
    if (isnew) ++n_used;
    if (lane == 0) colors[v] = chosen;

    // ---- shift pipelined state ----
#pragma unroll
    for (int j = 0; j < 4; ++j) {
      plc[j] = pln[j]; erc[j] = ern[j]; bw[j] = bwn[j];
    }
    plcX = plnX; ercX = ernX; bw8 = bwn8;
    nbrv = nbrn; nbrn = nbrn2; chosen_prev = chosen;
  }

  for (int i = lane; i < NV; i += 64) out[i] = (float)colors[i];
  if (lane == 0)
    out[NV] = (((float)n_used) - baseline[0]) * logp / 8192.0f;
}

// ---------------------------------------------------------------------------
extern "C" void kernel_launch(void* const* d_in, const int* in_sizes, int n_in,
                              void* d_out, int out_size, void* d_ws, size_t ws_size,
                              hipStream_t stream) {
  const float* emb      = (const float*)d_in[0];
  const int*   nbr      = (const int*)d_in[1];
  const float* W1       = (const float*)d_in[2];
  const float* b1       = (const float*)d_in[3];
  const float* W2       = (const float*)d_in[4];
  const float* b2       = (const float*)d_in[5];
  const float* W3       = (const float*)d_in[6];
  const float* b3       = (const float*)d_in[7];
  const float* baseline = (const float*)d_in[8];
  float* out = (float*)d_out;

  char* ws = (char*)d_ws;
  float* g     = (float*)ws;                               // 2 KB
  float* plbuf = (float*)(ws + 2048);                      // 8192*260*4 B
  float* erbuf = (float*)(ws + 2048 + NV * RSTRIDE * 4);   // 8192*260*4 B
  float* part  = erbuf;  // alias: consumed by colmean_fin BEFORE mlp3g writes er

  colmean_part<<<64, 256, 0, stream>>>(emb, part);
  colmean_fin<<<1, 256, 0, stream>>>(part, g);
  mlp3g<<<NV / TV, 256, 0, stream>>>(emb, g, W1, b1, W2, b2, W3, b3, plbuf, erbuf);
  scan3<<<1, 128, 0, stream>>>(nbr, plbuf, erbuf, baseline, out);
}

// Round 4
// 5457.439 us; speedup vs baseline: 3.7539x; 1.4949x over previous
//
#include <hip/hip_runtime.h>
#include <stdint.h>
#include <math.h>

#define NV 8192
#define EMB 512
#define CLS 257
#define DEG 32
#define TV 16
#define RSTRIDE 260   // padded row stride (multiple of 4 floats -> 16B aligned)
#define NEGINF (-INFINITY)

// ---------------------------------------------------------------------------
// Threefry-2x32, 20 rounds — exactly JAX's _threefry2x32. constexpr so the
// input-independent key chain (seed 42) can be baked in at compile time.
// ---------------------------------------------------------------------------
struct KP { uint32_t a, b; };

__host__ __device__ constexpr KP tfc(uint32_t k0, uint32_t k1,
                                     uint32_t x0, uint32_t x1) {
  const uint32_t ks2 = k0 ^ k1 ^ 0x1BD11BDAu;
  uint32_t v0 = x0 + k0, v1 = x1 + k1;
#define QR(r) { v0 += v1; v1 = (v1 << (r)) | (v1 >> (32 - (r))); v1 ^= v0; }
  QR(13) QR(15) QR(26) QR(6)
  v0 += k1;  v1 += ks2 + 1u;
  QR(17) QR(29) QR(16) QR(24)
  v0 += ks2; v1 += k0 + 2u;
  QR(13) QR(15) QR(26) QR(6)
  v0 += k0;  v1 += k1 + 3u;
  QR(17) QR(29) QR(16) QR(24)
  v0 += k1;  v1 += ks2 + 4u;
  QR(13) QR(15) QR(26) QR(6)
  v0 += ks2; v1 += k0 + 5u;
#undef QR
  return KP{v0, v1};
}

struct Seg { KP e[256]; };
constexpr Seg mkseg(KP s) {
  Seg g{};
  g.e[0] = s;
  for (int i = 1; i < 256; ++i) g.e[i] = tfc(g.e[i - 1].a, g.e[i - 1].b, 0u, 0u);
  return g;
}
#define NXTSEG(prev) mkseg(tfc(prev.e[255].a, prev.e[255].b, 0u, 0u))
constexpr Seg SG0 = mkseg(KP{0u, 42u});
constexpr Seg SG1 = NXTSEG(SG0);   constexpr Seg SG2 = NXTSEG(SG1);
constexpr Seg SG3 = NXTSEG(SG2);   constexpr Seg SG4 = NXTSEG(SG3);
constexpr Seg SG5 = NXTSEG(SG4);   constexpr Seg SG6 = NXTSEG(SG5);
constexpr Seg SG7 = NXTSEG(SG6);   constexpr Seg SG8 = NXTSEG(SG7);
constexpr Seg SG9 = NXTSEG(SG8);   constexpr Seg SG10 = NXTSEG(SG9);
constexpr Seg SG11 = NXTSEG(SG10); constexpr Seg SG12 = NXTSEG(SG11);
constexpr Seg SG13 = NXTSEG(SG12); constexpr Seg SG14 = NXTSEG(SG13);
constexpr Seg SG15 = NXTSEG(SG14); constexpr Seg SG16 = NXTSEG(SG15);
constexpr Seg SG17 = NXTSEG(SG16); constexpr Seg SG18 = NXTSEG(SG17);
constexpr Seg SG19 = NXTSEG(SG18); constexpr Seg SG20 = NXTSEG(SG19);
constexpr Seg SG21 = NXTSEG(SG20); constexpr Seg SG22 = NXTSEG(SG21);
constexpr Seg SG23 = NXTSEG(SG22); constexpr Seg SG24 = NXTSEG(SG23);
constexpr Seg SG25 = NXTSEG(SG24); constexpr Seg SG26 = NXTSEG(SG25);
constexpr Seg SG27 = NXTSEG(SG26); constexpr Seg SG28 = NXTSEG(SG27);
constexpr Seg SG29 = NXTSEG(SG28); constexpr Seg SG30 = NXTSEG(SG29);
constexpr Seg SG31 = NXTSEG(SG30);

struct KT { uint32_t hi[8192]; uint32_t lo[8192]; };
constexpr KT mkkt() {
  KT t{};
  const Seg* sg[32] = {
    &SG0,  &SG1,  &SG2,  &SG3,  &SG4,  &SG5,  &SG6,  &SG7,
    &SG8,  &SG9,  &SG10, &SG11, &SG12, &SG13, &SG14, &SG15,
    &SG16, &SG17, &SG18, &SG19, &SG20, &SG21, &SG22, &SG23,
    &SG24, &SG25, &SG26, &SG27, &SG28, &SG29, &SG30, &SG31 };
  for (int s = 0; s < 32; ++s)
    for (int i = 0; i < 256; ++i) {
      const int v = 1 + s * 256 + i;
      if (v < 8192) { t.hi[v] = sg[s]->e[i].a; t.lo[v] = sg[s]->e[i].b; }
    }
  return t;
}
__device__ const KT KEYS = mkkt();

// ---------------------------------------------------------------------------
// K1: graph_emb = mean(embeddings, axis=0)
// ---------------------------------------------------------------------------
__global__ __launch_bounds__(256) void colmean_part(const float* __restrict__ emb,
                                                    float* __restrict__ part) {
  const int b = blockIdx.x;
  const int t = threadIdx.x;
  for (int j = t; j < EMB; j += 256) {
    float s = 0.f;
    const int r0 = b * 128;
    for (int r = 0; r < 128; ++r) s += emb[(size_t)(r0 + r) * EMB + j];
    part[(size_t)b * EMB + j] = s;
  }
}

__global__ __launch_bounds__(256) void colmean_fin(const float* __restrict__ part,
                                                   float* __restrict__ g) {
  const int t = threadIdx.x;
  for (int j = t; j < EMB; j += 256) {
    float s = 0.f;
    for (int b = 0; b < 64; ++b) s += part[(size_t)b * EMB + j];
    g[j] = s / 8192.0f;
  }
}

// ---------------------------------------------------------------------------
// K2: fused 3-layer MLP (bit-identical math to round-3) + epilogue:
// pl[] = li + gumbel, er[] = exp(li - rowmax).
// ---------------------------------------------------------------------------
__global__ __launch_bounds__(256) void mlp3g(
    const float* __restrict__ emb, const float* __restrict__ g,
    const float* __restrict__ W1, const float* __restrict__ b1,
    const float* __restrict__ W2, const float* __restrict__ b2,
    const float* __restrict__ W3, const float* __restrict__ b3,
    float* __restrict__ pl, float* __restrict__ er)
{
  __shared__ float xs[TV][68];
  __shared__ float gs[EMB];
  __shared__ float h1s[TV][EMB];
  __shared__ float h2s[TV][400];
  __shared__ float redw[TV][4];
  __shared__ float li256s[TV];
  __shared__ float mrs[TV];

  const int t  = threadIdx.x;
  const int tx = t & 63;
  const int ty = t >> 6;
  const int v0 = blockIdx.x * TV;

  for (int j = t; j < EMB; j += 256) gs[j] = g[j];

  float acc[4][8];
#pragma unroll
  for (int a = 0; a < 4; ++a)
#pragma unroll
    for (int b = 0; b < 8; ++b) acc[a][b] = 0.f;

  for (int kc = 0; kc < 8; ++kc) {
    __syncthreads();
    {
      const int vv = t >> 4;
      const int kk = (t & 15) << 2;
      const float4 s4 = *reinterpret_cast<const float4*>(
          &emb[(size_t)(v0 + vv) * EMB + kc * 64 + kk]);
      xs[vv][kk] = s4.x; xs[vv][kk + 1] = s4.y;
      xs[vv][kk + 2] = s4.z; xs[vv][kk + 3] = s4.w;
    }
    __syncthreads();
    float cacc[4][8];
#pragma unroll
    for (int a = 0; a < 4; ++a)
#pragma unroll
      for (int b = 0; b < 8; ++b) cacc[a][b] = 0.f;
    for (int kk = 0; kk < 64; ++kk) {
      const int k = kc * 64 + kk;
      float w[8];
#pragma unroll
      for (int jj = 0; jj < 8; ++jj) w[jj] = W1[(size_t)k * EMB + tx + 64 * jj];
      float xv[4];
#pragma unroll
      for (int vv = 0; vv < 4; ++vv) xv[vv] = xs[ty * 4 + vv][kk];
#pragma unroll
      for (int vv = 0; vv < 4; ++vv)
#pragma unroll
        for (int jj = 0; jj < 8; ++jj)
          cacc[vv][jj] = fmaf(xv[vv], w[jj], cacc[vv][jj]);
    }
#pragma unroll
    for (int a = 0; a < 4; ++a)
#pragma unroll
      for (int b = 0; b < 8; ++b) acc[a][b] += cacc[a][b];
  }

  float gacc[8];
#pragma unroll
  for (int b = 0; b < 8; ++b) gacc[b] = 0.f;
  for (int kc = 0; kc < 8; ++kc) {
    float cg[8];
#pragma unroll
    for (int b = 0; b < 8; ++b) cg[b] = 0.f;
    for (int kk = 0; kk < 64; ++kk) {
      const int k = kc * 64 + kk;
      const float gv = gs[k];
#pragma unroll
      for (int jj = 0; jj < 8; ++jj)
        cg[jj] = fmaf(gv, W1[(size_t)(EMB + k) * EMB + tx + 64 * jj], cg[jj]);
    }
#pragma unroll
    for (int b = 0; b < 8; ++b) gacc[b] += cg[b];
  }

#pragma unroll
  for (int jj = 0; jj < 8; ++jj) {
    const int j = tx + 64 * jj;
    const float bj = b1[j];
#pragma unroll
    for (int vv = 0; vv < 4; ++vv) {
      float h = (acc[vv][jj] + gacc[jj]) + bj;
      h = (h >= 0.f) ? h : 0.01f * h;
      h1s[ty * 4 + vv][j] = h;
    }
  }
  __syncthreads();

  const int j2a = t;
  const int j2b = t + 256;
  float a2[TV], a2b[TV];
#pragma unroll
  for (int vv = 0; vv < TV; ++vv) { a2[vv] = 0.f; a2b[vv] = 0.f; }
  for (int kc = 0; kc < 8; ++kc) {
    float c2[TV], c2b[TV];
#pragma unroll
    for (int vv = 0; vv < TV; ++vv) { c2[vv] = 0.f; c2b[vv] = 0.f; }
    for (int kk = 0; kk < 64; ++kk) {
      const int k = kc * 64 + kk;
      const float w0  = W2[(size_t)k * 400 + j2a];
      const float w1v = (j2b < 400) ? W2[(size_t)k * 400 + j2b] : 0.f;
#pragma unroll
      for (int vv = 0; vv < TV; ++vv) {
        const float hv = h1s[vv][k];
        c2[vv]  = fmaf(hv, w0,  c2[vv]);
        c2b[vv] = fmaf(hv, w1v, c2b[vv]);
      }
    }
#pragma unroll
    for (int vv = 0; vv < TV; ++vv) { a2[vv] += c2[vv]; a2b[vv] += c2b[vv]; }
  }
  {
    const float bja = b2[j2a];
#pragma unroll
    for (int vv = 0; vv < TV; ++vv) {
      float h = a2[vv] + bja;
      h2s[vv][j2a] = (h >= 0.f) ? h : 0.01f * h;
    }
    if (j2b < 400) {
      const float bjb = b2[j2b];
#pragma unroll
      for (int vv = 0; vv < TV; ++vv) {
        float h = a2b[vv] + bjb;
        h2s[vv][j2b] = (h >= 0.f) ? h : 0.01f * h;
      }
    }
  }
  __syncthreads();

  float a3[TV], a3x[TV];
#pragma unroll
  for (int vv = 0; vv < TV; ++vv) { a3[vv] = 0.f; a3x[vv] = 0.f; }
  for (int kc = 0; kc < 8; ++kc) {
    float c3[TV], c3x[TV];
#pragma unroll
    for (int vv = 0; vv < TV; ++vv) { c3[vv] = 0.f; c3x[vv] = 0.f; }
    for (int kk = 0; kk < 50; ++kk) {
      const int k = kc * 50 + kk;
      const float w0 = W3[(size_t)k * CLS + t];
      const float wx = (t == 0) ? W3[(size_t)k * CLS + 256] : 0.f;
#pragma unroll
      for (int vv = 0; vv < TV; ++vv) {
        const float hv = h2s[vv][k];
        c3[vv]  = fmaf(hv, w0, c3[vv]);
        c3x[vv] = fmaf(hv, wx, c3x[vv]);
      }
    }
#pragma unroll
    for (int vv = 0; vv < TV; ++vv) { a3[vv] += c3[vv]; a3x[vv] += c3x[vv]; }
  }

  const float bj = b3[t];
  float li_[TV];
#pragma unroll
  for (int vv = 0; vv < TV; ++vv) li_[vv] = a3[vv] + bj;

#pragma unroll
  for (int vv = 0; vv < TV; ++vv) {
    float m = li_[vv];
#pragma unroll
    for (int off = 1; off < 64; off <<= 1) m = fmaxf(m, __shfl_xor(m, off));
    if ((t & 63) == 0) redw[vv][t >> 6] = m;
  }
  if (t == 0) {
    const float bx = b3[256];
#pragma unroll
    for (int vv = 0; vv < TV; ++vv) li256s[vv] = a3x[vv] + bx;
  }
  __syncthreads();
  if (t < TV) {
    const float m = fmaxf(fmaxf(redw[t][0], redw[t][1]),
                          fmaxf(redw[t][2], redw[t][3]));
    mrs[t] = fmaxf(m, li256s[t]);
  }
  __syncthreads();

#pragma unroll
  for (int vv = 0; vv < TV; ++vv) {
    const int v = v0 + vv;
    const float li = li_[vv];
    const KP sk = tfc(KEYS.hi[v], KEYS.lo[v], 0u, 1u);
    const KP o  = tfc(sk.a, sk.b, 0u, (uint32_t)t);
    const uint32_t bb = o.a ^ o.b;
    const float f = __uint_as_float(0x3f800000u | (bb >> 9)) - 1.0f;
    const float u = fmaxf(1.17549435e-38f, f);
    const float gg = -logf(-logf(u));
    pl[(size_t)v * RSTRIDE + t] = li + gg;
    er[(size_t)v * RSTRIDE + t] = expf(li - mrs[vv]);
  }
  if (t == 0) {
    const float bx = b3[256];
#pragma unroll
    for (int vv = 0; vv < TV; ++vv) {
      const int v = v0 + vv;
      const float li = a3x[vv] + bx;
      const KP sk = tfc(KEYS.hi[v], KEYS.lo[v], 0u, 1u);
      const KP o  = tfc(sk.a, sk.b, 0u, 256u);
      const uint32_t bb = o.a ^ o.b;
      const float f = __uint_as_float(0x3f800000u | (bb >> 9)) - 1.0f;
      const float u = fmaxf(1.17549435e-38f, f);
      const float gg = -logf(-logf(u));
      pl[(size_t)v * RSTRIDE + 256] = li + gg;
      er[(size_t)v * RSTRIDE + 256] = expf(li - mrs[vv]);
    }
  }
}

// ---------------------------------------------------------------------------
// helpers for the scan
// ---------------------------------------------------------------------------
#define DPPF(CTRL, OLDI, X) \
  __builtin_amdgcn_update_dpp((int)(OLDI), (X), (CTRL), 0xF, 0xF, false)

// packed-key argmax round: key = (ordmap(pl) << 32) | ~idx
#define ARED64(CTRL) {                                          \
  const uint32_t oh = (uint32_t)DPPF(CTRL, 0, (int)fh);         \
  const uint32_t ol = (uint32_t)DPPF(CTRL, 0, (int)fl);         \
  const bool tk = ((((uint64_t)oh << 32) | ol) >                \
                   (((uint64_t)fh << 32) | fl));                \
  fh = tk ? oh : fh; fl = tk ? ol : fl; }

#define SRED(CTRL) { S += __int_as_float(DPPF(CTRL, 0, __float_as_int(S))); }

__device__ __forceinline__ uint32_t ordmap(float f) {
  const uint32_t s = __float_as_uint(f);
  return s ^ (0x80000000u | (uint32_t)((int32_t)s >> 31));
}

#define WG_SCOPE __HIP_MEMORY_SCOPE_WORKGROUP

// ---------------------------------------------------------------------------
// K3: producer-consumer scan, argmax only. Consumer records raw|(n_used<<16)
// per step; logp is recomputed in parallel afterwards (logp_part/finalize).
// ---------------------------------------------------------------------------
__global__ __launch_bounds__(128) void scan4(
    const int* __restrict__ nbrG, const float* __restrict__ plG,
    unsigned* __restrict__ rawnu, float* __restrict__ out)
{
  __shared__ int colors[NV];          // 32 KB
  __shared__ float plR[32][RSTRIDE];  // 33.3 KB ring (4 chunks x 8 rows)
  __shared__ int nbrRing[1024];       // 4 KB ring (4 chunks x 8 rows x 32)
  __shared__ unsigned bbuf[2][16];
  __shared__ int prod_done, cons_done;

  const int t = threadIdx.x;
  const int lane = t & 63;
  const int ln32 = lane & 31;

  for (int i = t; i < NV; i += 128) colors[i] = -1;
  if (t == 0) { colors[0] = 0; prod_done = 0; cons_done = 0; }
  __syncthreads();

  if (t >= 64) {
    // ================= producer wave =================
    for (int pc = 0; pc < 1024; ++pc) {
      while (__hip_atomic_load(&cons_done, __ATOMIC_ACQUIRE, WG_SCOPE) < pc - 3)
        __builtin_amdgcn_s_sleep(1);
      float4 pbuf[8]; float pX[8];
#pragma unroll
      for (int r = 0; r < 8; ++r) {
        const size_t base = (size_t)(pc * 8 + r) * RSTRIDE;
        pbuf[r] = *reinterpret_cast<const float4*>(plG + base + 4 * lane);
        pX[r] = plG[base + 256];
      }
      const int4 nb4 = *reinterpret_cast<const int4*>(nbrG + pc * 256 + 4 * lane);
#pragma unroll
      for (int r = 0; r < 8; ++r) {
        const int slot = (pc * 8 + r) & 31;
        *reinterpret_cast<float4*>(&plR[slot][4 * lane]) = pbuf[r];
        if (lane == 0) plR[slot][256] = pX[r];
      }
      *reinterpret_cast<int4*>(&nbrRing[((pc & 3) << 8) + 4 * lane]) = nb4;
      if (lane == 0)
        __hip_atomic_store(&prod_done, pc + 1, __ATOMIC_RELEASE, WG_SCOPE);
    }
    return;
  }

  // ================= consumer wave =================
  while (__hip_atomic_load(&prod_done, __ATOMIC_ACQUIRE, WG_SCOPE) < 2) {}

  const uint32_t KL0 = ~(uint32_t)lane;
  const uint32_t KL1 = ~(uint32_t)(lane + 64);
  const uint32_t KL2 = ~(uint32_t)(lane + 128);
  const uint32_t KL3 = ~(uint32_t)(lane + 192);
  const uint32_t KLX = ~256u;

  uint32_t khc[4], khcX;
  unsigned bw[4], bw8;
  bool hf;
  int nbrn;
  {
    const int nb1 = nbrRing[(1 << 5) + ln32];            // row 1, chunk 0
    bbuf[1][lane & 15] = 0u;
    hf = (__ballot(nb1 == 0) != 0ULL);
    const int cg0 = colors[nb1];
    if (cg0 >= 0) atomicOr(&bbuf[1][cg0 >> 5], 1u << (cg0 & 31));
#pragma unroll
    for (int j = 0; j < 4; ++j) {
      khc[j] = ordmap(plR[1][lane + 64 * j]);
      bw[j] = bbuf[1][(lane >> 5) + 2 * j];
    }
    khcX = ordmap(plR[1][256]);
    bw8 = bbuf[1][8];
    nbrn = nbrRing[(2 << 5) + ln32];                      // row 2, chunk 0
  }

  int chosen_prev = 0;
  int n_used = 1;

  for (int v = 1; v < NV; ++v) {
    const int vp1 = (v + 1 < NV) ? v + 1 : NV - 1;
    const int vp2 = (v + 2 < NV) ? v + 2 : NV - 1;

    // ---- chunk sync (1/8 iters) ----
    if ((v & 7) == 7) {
      if (lane == 0)
        __hip_atomic_store(&cons_done, (v + 1) >> 3, __ATOMIC_RELEASE, WG_SCOPE);
      int tgt = ((v + 1) >> 3) + 2;
      tgt = tgt > 1024 ? 1024 : tgt;
      while (__hip_atomic_load(&prod_done, __ATOMIC_ACQUIRE, WG_SCOPE) < tgt) {}
    }

    // ---- prefetch phase (off critical path): build state for v+1 ----
    const int sN = vp1 & 31;
    uint32_t khn[4], khnX;
#pragma unroll
    for (int j = 0; j < 4; ++j) khn[j] = ordmap(plR[sN][lane + 64 * j]);
    khnX = ordmap(plR[sN][256]);
    const int nbrn2 = nbrRing[(((vp2 >> 3) & 3) << 8) + ((vp2 & 7) << 5) + ln32];

    const int nb = vp1 & 1;
    bbuf[nb][lane & 15] = 0u;
    const bool hfn = (__ballot(nbrn == v) != 0ULL);
    const int cgn = colors[nbrn];                 // stale gather (misses only v)
    if (cgn >= 0) atomicOr(&bbuf[nb][cgn >> 5], 1u << (cgn & 31));
    unsigned bwn[4];
#pragma unroll
    for (int j = 0; j < 4; ++j) bwn[j] = bbuf[nb][(lane >> 5) + 2 * j];
    const unsigned bwn8 = bbuf[nb][8];

    // ---- critical phase for v ----
    const int fixc = chosen_prev;
    const int nu = n_used;
    bool mk[4];
#pragma unroll
    for (int j = 0; j < 4; ++j) {
      const int c = lane + 64 * j;
      mk[j] = (((bw[j] >> ln32) & 1u) != 0u)
           || (hf && c == fixc)
           || (c >= nu);
    }
    const bool mkX = ((bw8 & 1u) != 0u) || (hf && fixc == 256);

    uint64_t best = ((uint64_t)(mk[0] ? 0u : khc[0]) << 32) | (mk[0] ? 0u : KL0);
    {
      const uint64_t c1 = ((uint64_t)(mk[1] ? 0u : khc[1]) << 32) | (mk[1] ? 0u : KL1);
      if (c1 > best) best = c1;
      const uint64_t c2 = ((uint64_t)(mk[2] ? 0u : khc[2]) << 32) | (mk[2] ? 0u : KL2);
      if (c2 > best) best = c2;
      const uint64_t c3 = ((uint64_t)(mk[3] ? 0u : khc[3]) << 32) | (mk[3] ? 0u : KL3);
      if (c3 > best) best = c3;
      const uint64_t cX = ((uint64_t)(mkX ? 0u : khcX) << 32) | (mkX ? 0u : KLX);
      if (cX > best) best = cX;
    }
    uint32_t fh = (uint32_t)(best >> 32), fl = (uint32_t)best;
    ARED64(0x111) ARED64(0x112) ARED64(0x114) ARED64(0x118)
    ARED64(0x142) ARED64(0x143)
    const uint32_t kl63 = (uint32_t)__builtin_amdgcn_readlane((int)fl, 63);
    const int raw = (int)(~kl63);

    const bool isnew = (raw == 256);
    const int nuB = n_used;
    const int chosen = isnew ? nuB : raw;
    if (isnew) ++n_used;
    if (lane == 0) {
      colors[v] = chosen;
      rawnu[v] = (unsigned)raw | ((unsigned)nuB << 16);
    }

    // ---- shift pipelined state ----
#pragma unroll
    for (int j = 0; j < 4; ++j) { khc[j] = khn[j]; bw[j] = bwn[j]; }
    khcX = khnX; bw8 = bwn8; hf = hfn;
    nbrn = nbrn2; chosen_prev = chosen;
  }

  for (int i = lane; i < NV; i += 64) out[i] = (float)colors[i];
}

// ---------------------------------------------------------------------------
// K4: parallel logp recomputation. One wave per vertex (4 waves/block,
// 64 blocks, 32 vertices per wave). No barriers; wave-private LDS ban masks.
// Mirrors round-3's S-reduction/praw/p/logf bit-for-bit; f64 accumulation.
// ---------------------------------------------------------------------------
__global__ __launch_bounds__(256) void logp_part(
    const float* __restrict__ outF, const int* __restrict__ nbrG,
    const float* __restrict__ er, const unsigned* __restrict__ rawnu,
    double* __restrict__ partd)
{
  __shared__ unsigned bb[4][16];
  const int t = threadIdx.x;
  const int w = t >> 6;
  const int lane = t & 63;
  const int ln32 = lane & 31;
  const int b = blockIdx.x;

  double a = 0.0;
  for (int i = 0; i < 32; ++i) {
    const int v = b * 128 + w * 32 + i;
    if (v == 0) continue;
    const unsigned val = rawnu[v];
    const int raw = (int)(val & 0xFFFFu);
    const int nu  = (int)(val >> 16);

    bb[w][lane & 15] = 0u;
    const int u = nbrG[(size_t)v * DEG + ln32];
    const int cu = (u < v) ? (int)outF[u] : -1;
    if (cu >= 0) atomicOr(&bb[w][cu >> 5], 1u << (cu & 31));
    unsigned bwp[4];
#pragma unroll
    for (int j = 0; j < 4; ++j) bwp[j] = bb[w][(lane >> 5) + 2 * j];
    const unsigned bw8 = bb[w][8];

    const size_t base = (size_t)v * RSTRIDE;
    bool mk[4];
    float e[4];
#pragma unroll
    for (int j = 0; j < 4; ++j) {
      const int c = lane + 64 * j;
      mk[j] = (((bwp[j] >> ln32) & 1u) != 0u) || (c >= nu);
      e[j] = mk[j] ? 0.f : er[base + c];
    }
    const bool mkX = ((bw8 & 1u) != 0u);
    const float eX = er[base + 256];
    const float e4 = (!mkX && lane == 0) ? eX : 0.f;

    float S = ((e[0] + e[1]) + (e[2] + e[3])) + e4;
    SRED(0x111) SRED(0x112) SRED(0x114) SRED(0x118) SRED(0x142) SRED(0x143)
    const float Sall = __int_as_float(
        __builtin_amdgcn_readlane(__float_as_int(S), 63));

    const bool isnew = (raw == 256);
    const int jsel  = isnew ? 4 : (raw >> 6);
    const int owner = isnew ? 0 : (raw & 63);
    const float cand = (jsel == 0) ? e[0] : (jsel == 1) ? e[1]
                     : (jsel == 2) ? e[2] : (jsel == 3) ? e[3] : e4;
    const float praw = __int_as_float(
        __builtin_amdgcn_readlane(__float_as_int(cand), owner));

    const float p = praw / Sall;
    a += (double)(logf(p + 1e-8f) - logf(1e-8f));
  }
  if (lane == 0) partd[b * 4 + w] = a;
}

__global__ __launch_bounds__(64) void finalize(
    const double* __restrict__ partd, const unsigned* __restrict__ rawnu,
    const float* __restrict__ baseline, float* __restrict__ out)
{
  if (threadIdx.x == 0) {
    double lp = 0.0;
    for (int i = 0; i < 256; ++i) lp += partd[i];
    const unsigned val = rawnu[NV - 1];
    const unsigned nf = (val >> 16) + (((val & 0xFFFFu) == 256u) ? 1u : 0u);
    out[NV] = ((float)nf - baseline[0]) * (float)lp / 8192.0f;
  }
}

// ---------------------------------------------------------------------------
extern "C" void kernel_launch(void* const* d_in, const int* in_sizes, int n_in,
                              void* d_out, int out_size, void* d_ws, size_t ws_size,
                              hipStream_t stream) {
  const float* emb      = (const float*)d_in[0];
  const int*   nbr      = (const int*)d_in[1];
  const float* W1       = (const float*)d_in[2];
  const float* b1       = (const float*)d_in[3];
  const float* W2       = (const float*)d_in[4];
  const float* b2       = (const float*)d_in[5];
  const float* W3       = (const float*)d_in[6];
  const float* b3       = (const float*)d_in[7];
  const float* baseline = (const float*)d_in[8];
  float* out = (float*)d_out;

  char* ws = (char*)d_ws;
  float* g     = (float*)ws;                               // 2 KB
  float* plbuf = (float*)(ws + 2048);                      // 8192*260*4 B
  float* erbuf = (float*)(ws + 2048 + NV * RSTRIDE * 4);   // 8192*260*4 B
  float* part  = erbuf;  // alias: consumed by colmean_fin BEFORE mlp3g writes er
  // rawnu/partd alias long-dead head of plbuf (rows consumed before writes land):
  unsigned* rawnu = (unsigned*)(ws + 2048);                // 32 KB  (pl rows 0..31)
  double*   partd = (double*)(ws + 2048 + 65536);          // 2 KB   (pl rows ~63)

  colmean_part<<<64, 256, 0, stream>>>(emb, part);
  colmean_fin<<<1, 256, 0, stream>>>(part, g);
  mlp3g<<<NV / TV, 256, 0, stream>>>(emb, g, W1, b1, W2, b2, W3, b3, plbuf, erbuf);
  scan4<<<1, 128, 0, stream>>>(nbr, plbuf, rawnu, out);
  logp_part<<<64, 256, 0, stream>>>((const float*)out, nbr, erbuf, rawnu, partd);
  finalize<<<1, 64, 0, stream>>>(partd, rawnu, baseline, out);
}

// Round 5
// 4409.875 us; speedup vs baseline: 4.6457x; 1.2375x over previous
//
#include <hip/hip_runtime.h>
#include <stdint.h>
#include <math.h>

#define NV 8192
#define EMB 512
#define CLS 257
#define DEG 32
#define TV 16
#define RSTRIDE 260   // padded row stride in floats (1040 B, 16B-aligned)
#define NEGINF (-INFINITY)

// ---------------------------------------------------------------------------
// Threefry-2x32, 20 rounds — exactly JAX's _threefry2x32. constexpr so the
// input-independent key chain (seed 42) can be baked in at compile time.
// ---------------------------------------------------------------------------
struct KP { uint32_t a, b; };

__host__ __device__ constexpr KP tfc(uint32_t k0, uint32_t k1,
                                     uint32_t x0, uint32_t x1) {
  const uint32_t ks2 = k0 ^ k1 ^ 0x1BD11BDAu;
  uint32_t v0 = x0 + k0, v1 = x1 + k1;
#define QR(r) { v0 += v1; v1 = (v1 << (r)) | (v1 >> (32 - (r))); v1 ^= v0; }
  QR(13) QR(15) QR(26) QR(6)
  v0 += k1;  v1 += ks2 + 1u;
  QR(17) QR(29) QR(16) QR(24)
  v0 += ks2; v1 += k0 + 2u;
  QR(13) QR(15) QR(26) QR(6)
  v0 += k0;  v1 += k1 + 3u;
  QR(17) QR(29) QR(16) QR(24)
  v0 += k1;  v1 += ks2 + 4u;
  QR(13) QR(15) QR(26) QR(6)
  v0 += ks2; v1 += k0 + 5u;
#undef QR
  return KP{v0, v1};
}

struct Seg { KP e[256]; };
constexpr Seg mkseg(KP s) {
  Seg g{};
  g.e[0] = s;
  for (int i = 1; i < 256; ++i) g.e[i] = tfc(g.e[i - 1].a, g.e[i - 1].b, 0u, 0u);
  return g;
}
#define NXTSEG(prev) mkseg(tfc(prev.e[255].a, prev.e[255].b, 0u, 0u))
constexpr Seg SG0 = mkseg(KP{0u, 42u});
constexpr Seg SG1 = NXTSEG(SG0);   constexpr Seg SG2 = NXTSEG(SG1);
constexpr Seg SG3 = NXTSEG(SG2);   constexpr Seg SG4 = NXTSEG(SG3);
constexpr Seg SG5 = NXTSEG(SG4);   constexpr Seg SG6 = NXTSEG(SG5);
constexpr Seg SG7 = NXTSEG(SG6);   constexpr Seg SG8 = NXTSEG(SG7);
constexpr Seg SG9 = NXTSEG(SG8);   constexpr Seg SG10 = NXTSEG(SG9);
constexpr Seg SG11 = NXTSEG(SG10); constexpr Seg SG12 = NXTSEG(SG11);
constexpr Seg SG13 = NXTSEG(SG12); constexpr Seg SG14 = NXTSEG(SG13);
constexpr Seg SG15 = NXTSEG(SG14); constexpr Seg SG16 = NXTSEG(SG15);
constexpr Seg SG17 = NXTSEG(SG16); constexpr Seg SG18 = NXTSEG(SG17);
constexpr Seg SG19 = NXTSEG(SG18); constexpr Seg SG20 = NXTSEG(SG19);
constexpr Seg SG21 = NXTSEG(SG20); constexpr Seg SG22 = NXTSEG(SG21);
constexpr Seg SG23 = NXTSEG(SG22); constexpr Seg SG24 = NXTSEG(SG23);
constexpr Seg SG25 = NXTSEG(SG24); constexpr Seg SG26 = NXTSEG(SG25);
constexpr Seg SG27 = NXTSEG(SG26); constexpr Seg SG28 = NXTSEG(SG27);
constexpr Seg SG29 = NXTSEG(SG28); constexpr Seg SG30 = NXTSEG(SG29);
constexpr Seg SG31 = NXTSEG(SG30);

struct KT { uint32_t hi[8192]; uint32_t lo[8192]; };
constexpr KT mkkt() {
  KT t{};
  const Seg* sg[32] = {
    &SG0,  &SG1,  &SG2,  &SG3,  &SG4,  &SG5,  &SG6,  &SG7,
    &SG8,  &SG9,  &SG10, &SG11, &SG12, &SG13, &SG14, &SG15,
    &SG16, &SG17, &SG18, &SG19, &SG20, &SG21, &SG22, &SG23,
    &SG24, &SG25, &SG26, &SG27, &SG28, &SG29, &SG30, &SG31 };
  for (int s = 0; s < 32; ++s)
    for (int i = 0; i < 256; ++i) {
      const int v = 1 + s * 256 + i;
      if (v < 8192) { t.hi[v] = sg[s]->e[i].a; t.lo[v] = sg[s]->e[i].b; }
    }
  return t;
}
__device__ const KT KEYS = mkkt();

// ---------------------------------------------------------------------------
// K1: graph_emb = mean(embeddings, axis=0)
// ---------------------------------------------------------------------------
__global__ __launch_bounds__(256) void colmean_part(const float* __restrict__ emb,
                                                    float* __restrict__ part) {
  const int b = blockIdx.x;
  const int t = threadIdx.x;
  for (int j = t; j < EMB; j += 256) {
    float s = 0.f;
    const int r0 = b * 128;
    for (int r = 0; r < 128; ++r) s += emb[(size_t)(r0 + r) * EMB + j];
    part[(size_t)b * EMB + j] = s;
  }
}

__global__ __launch_bounds__(256) void colmean_fin(const float* __restrict__ part,
                                                   float* __restrict__ g) {
  const int t = threadIdx.x;
  for (int j = t; j < EMB; j += 256) {
    float s = 0.f;
    for (int b = 0; b < 64; ++b) s += part[(size_t)b * EMB + j];
    g[j] = s / 8192.0f;
  }
}

// ---------------------------------------------------------------------------
// K2: fused 3-layer MLP (bit-identical math to round-4) + epilogue:
// pl[] = li + gumbel, er[] = exp(li - rowmax).
// ---------------------------------------------------------------------------
__global__ __launch_bounds__(256) void mlp3g(
    const float* __restrict__ emb, const float* __restrict__ g,
    const float* __restrict__ W1, const float* __restrict__ b1,
    const float* __restrict__ W2, const float* __restrict__ b2,
    const float* __restrict__ W3, const float* __restrict__ b3,
    float* __restrict__ pl, float* __restrict__ er)
{
  __shared__ float xs[TV][68];
  __shared__ float gs[EMB];
  __shared__ float h1s[TV][EMB];
  __shared__ float h2s[TV][400];
  __shared__ float redw[TV][4];
  __shared__ float li256s[TV];
  __shared__ float mrs[TV];

  const int t  = threadIdx.x;
  const int tx = t & 63;
  const int ty = t >> 6;
  const int v0 = blockIdx.x * TV;

  for (int j = t; j < EMB; j += 256) gs[j] = g[j];

  float acc[4][8];
#pragma unroll
  for (int a = 0; a < 4; ++a)
#pragma unroll
    for (int b = 0; b < 8; ++b) acc[a][b] = 0.f;

  for (int kc = 0; kc < 8; ++kc) {
    __syncthreads();
    {
      const int vv = t >> 4;
      const int kk = (t & 15) << 2;
      const float4 s4 = *reinterpret_cast<const float4*>(
          &emb[(size_t)(v0 + vv) * EMB + kc * 64 + kk]);
      xs[vv][kk] = s4.x; xs[vv][kk + 1] = s4.y;
      xs[vv][kk + 2] = s4.z; xs[vv][kk + 3] = s4.w;
    }
    __syncthreads();
    float cacc[4][8];
#pragma unroll
    for (int a = 0; a < 4; ++a)
#pragma unroll
      for (int b = 0; b < 8; ++b) cacc[a][b] = 0.f;
    for (int kk = 0; kk < 64; ++kk) {
      const int k = kc * 64 + kk;
      float w[8];
#pragma unroll
      for (int jj = 0; jj < 8; ++jj) w[jj] = W1[(size_t)k * EMB + tx + 64 * jj];
      float xv[4];
#pragma unroll
      for (int vv = 0; vv < 4; ++vv) xv[vv] = xs[ty * 4 + vv][kk];
#pragma unroll
      for (int vv = 0; vv < 4; ++vv)
#pragma unroll
        for (int jj = 0; jj < 8; ++jj)
          cacc[vv][jj] = fmaf(xv[vv], w[jj], cacc[vv][jj]);
    }
#pragma unroll
    for (int a = 0; a < 4; ++a)
#pragma unroll
      for (int b = 0; b < 8; ++b) acc[a][b] += cacc[a][b];
  }

  float gacc[8];
#pragma unroll
  for (int b = 0; b < 8; ++b) gacc[b] = 0.f;
  for (int kc = 0; kc < 8; ++kc) {
    float cg[8];
#pragma unroll
    for (int b = 0; b < 8; ++b) cg[b] = 0.f;
    for (int kk = 0; kk < 64; ++kk) {
      const int k = kc * 64 + kk;
      const float gv = gs[k];
#pragma unroll
      for (int jj = 0; jj < 8; ++jj)
        cg[jj] = fmaf(gv, W1[(size_t)(EMB + k) * EMB + tx + 64 * jj], cg[jj]);
    }
#pragma unroll
    for (int b = 0; b < 8; ++b) gacc[b] += cg[b];
  }

#pragma unroll
  for (int jj = 0; jj < 8; ++jj) {
    const int j = tx + 64 * jj;
    const float bj = b1[j];
#pragma unroll
    for (int vv = 0; vv < 4; ++vv) {
      float h = (acc[vv][jj] + gacc[jj]) + bj;
      h = (h >= 0.f) ? h : 0.01f * h;
      h1s[ty * 4 + vv][j] = h;
    }
  }
  __syncthreads();

  const int j2a = t;
  const int j2b = t + 256;
  float a2[TV], a2b[TV];
#pragma unroll
  for (int vv = 0; vv < TV; ++vv) { a2[vv] = 0.f; a2b[vv] = 0.f; }
  for (int kc = 0; kc < 8; ++kc) {
    float c2[TV], c2b[TV];
#pragma unroll
    for (int vv = 0; vv < TV; ++vv) { c2[vv] = 0.f; c2b[vv] = 0.f; }
    for (int kk = 0; kk < 64; ++kk) {
      const int k = kc * 64 + kk;
      const float w0  = W2[(size_t)k * 400 + j2a];
      const float w1v = (j2b < 400) ? W2[(size_t)k * 400 + j2b] : 0.f;
#pragma unroll
      for (int vv = 0; vv < TV; ++vv) {
        const float hv = h1s[vv][k];
        c2[vv]  = fmaf(hv, w0,  c2[vv]);
        c2b[vv] = fmaf(hv, w1v, c2b[vv]);
      }
    }
#pragma unroll
    for (int vv = 0; vv < TV; ++vv) { a2[vv] += c2[vv]; a2b[vv] += c2b[vv]; }
  }
  {
    const float bja = b2[j2a];
#pragma unroll
    for (int vv = 0; vv < TV; ++vv) {
      float h = a2[vv] + bja;
      h2s[vv][j2a] = (h >= 0.f) ? h : 0.01f * h;
    }
    if (j2b < 400) {
      const float bjb = b2[j2b];
#pragma unroll
      for (int vv = 0; vv < TV; ++vv) {
        float h = a2b[vv] + bjb;
        h2s[vv][j2b] = (h >= 0.f) ? h : 0.01f * h;
      }
    }
  }
  __syncthreads();

  float a3[TV], a3x[TV];
#pragma unroll
  for (int vv = 0; vv < TV; ++vv) { a3[vv] = 0.f; a3x[vv] = 0.f; }
  for (int kc = 0; kc < 8; ++kc) {
    float c3[TV], c3x[TV];
#pragma unroll
    for (int vv = 0; vv < TV; ++vv) { c3[vv] = 0.f; c3x[vv] = 0.f; }
    for (int kk = 0; kk < 50; ++kk) {
      const int k = kc * 50 + kk;
      const float w0 = W3[(size_t)k * CLS + t];
      const float wx = (t == 0) ? W3[(size_t)k * CLS + 256] : 0.f;
#pragma unroll
      for (int vv = 0; vv < TV; ++vv) {
        const float hv = h2s[vv][k];
        c3[vv]  = fmaf(hv, w0, c3[vv]);
        c3x[vv] = fmaf(hv, wx, c3x[vv]);
      }
    }
#pragma unroll
    for (int vv = 0; vv < TV; ++vv) { a3[vv] += c3[vv]; a3x[vv] += c3x[vv]; }
  }

  const float bj = b3[t];
  float li_[TV];
#pragma unroll
  for (int vv = 0; vv < TV; ++vv) li_[vv] = a3[vv] + bj;

#pragma unroll
  for (int vv = 0; vv < TV; ++vv) {
    float m = li_[vv];
#pragma unroll
    for (int off = 1; off < 64; off <<= 1) m = fmaxf(m, __shfl_xor(m, off));
    if ((t & 63) == 0) redw[vv][t >> 6] = m;
  }
  if (t == 0) {
    const float bx = b3[256];
#pragma unroll
    for (int vv = 0; vv < TV; ++vv) li256s[vv] = a3x[vv] + bx;
  }
  __syncthreads();
  if (t < TV) {
    const float m = fmaxf(fmaxf(redw[t][0], redw[t][1]),
                          fmaxf(redw[t][2], redw[t][3]));
    mrs[t] = fmaxf(m, li256s[t]);
  }
  __syncthreads();

#pragma unroll
  for (int vv = 0; vv < TV; ++vv) {
    const int v = v0 + vv;
    const float li = li_[vv];
    const KP sk = tfc(KEYS.hi[v], KEYS.lo[v], 0u, 1u);
    const KP o  = tfc(sk.a, sk.b, 0u, (uint32_t)t);
    const uint32_t bb = o.a ^ o.b;
    const float f = __uint_as_float(0x3f800000u | (bb >> 9)) - 1.0f;
    const float u = fmaxf(1.17549435e-38f, f);
    const float gg = -logf(-logf(u));
    pl[(size_t)v * RSTRIDE + t] = li + gg;
    er[(size_t)v * RSTRIDE + t] = expf(li - mrs[vv]);
  }
  if (t == 0) {
    const float bx = b3[256];
#pragma unroll
    for (int vv = 0; vv < TV; ++vv) {
      const int v = v0 + vv;
      const float li = a3x[vv] + bx;
      const KP sk = tfc(KEYS.hi[v], KEYS.lo[v], 0u, 1u);
      const KP o  = tfc(sk.a, sk.b, 0u, 256u);
      const uint32_t bb = o.a ^ o.b;
      const float f = __uint_as_float(0x3f800000u | (bb >> 9)) - 1.0f;
      const float u = fmaxf(1.17549435e-38f, f);
      const float gg = -logf(-logf(u));
      pl[(size_t)v * RSTRIDE + 256] = li + gg;
      er[(size_t)v * RSTRIDE + 256] = expf(li - mrs[vv]);
    }
  }
}

// ---------------------------------------------------------------------------
// helpers
// ---------------------------------------------------------------------------
#define DPPF(CTRL, OLDI, X) \
  __builtin_amdgcn_update_dpp((int)(OLDI), (X), (CTRL), 0xF, 0xF, false)
#define SRED(CTRL) { S += __int_as_float(DPPF(CTRL, 0, __float_as_int(S))); }

__device__ __forceinline__ uint32_t ordmap(float f) {
  const uint32_t s = __float_as_uint(f);
  return s ^ (0x80000000u | (uint32_t)((int32_t)s >> 31));
}

#define WG_SCOPE __HIP_MEMORY_SCOPE_WORKGROUP

// ---------------------------------------------------------------------------
// K2b: per-row descending sort of 257 perturbed logits by (ordmap(pl), ~idx).
// One wave per row; u64 bitonic over 512 padded elems in LDS. Result: first
// 320 u16 of each pl row are overwritten IN PLACE with the sorted class ids.
// ---------------------------------------------------------------------------
__global__ __launch_bounds__(256) void sortrows(float* __restrict__ plbuf) {
  __shared__ uint64_t keys[4][512];
  const int t = threadIdx.x;
  const int w = t >> 6;
  const int lane = t & 63;
  const int v = blockIdx.x * 4 + w;
  const float* row = plbuf + (size_t)v * RSTRIDE;

#pragma unroll
  for (int j = 0; j < 8; ++j) {
    const int i = lane + 64 * j;
    uint32_t om = 0u;
    if (i < CLS) om = ordmap(row[i]);
    keys[w][i] = ((uint64_t)om << 9) | (uint64_t)(511 - i);
  }
  __syncthreads();

  for (int k = 2; k <= 512; k <<= 1) {
    for (int j = k >> 1; j > 0; j >>= 1) {
#pragma unroll
      for (int m = 0; m < 4; ++m) {
        const int p  = lane + 64 * m;                       // pair id 0..255
        const int i  = ((p & ~(j - 1)) << 1) | (p & (j - 1));
        const int ix = i | j;
        const uint64_t a = keys[w][i], b = keys[w][ix];
        const bool sw = ((i & k) == 0) ? (a < b) : (a > b); // descending
        if (sw) { keys[w][i] = b; keys[w][ix] = a; }
      }
      __syncthreads();
    }
  }

  uint16_t* o16 = reinterpret_cast<uint16_t*>(plbuf) + (size_t)v * (RSTRIDE * 2);
#pragma unroll
  for (int j = 0; j < 5; ++j) {
    const int i = lane + 64 * j;
    if (i < 320) o16[i] = (uint16_t)(511u - (uint32_t)(keys[w][i] & 511u));
  }
}

// ---------------------------------------------------------------------------
// K3: producer-consumer scan over pre-sorted candidate lists. Critical phase
// = ballot over "first allowed in sorted order" (typically 1 ballot).
// ---------------------------------------------------------------------------
__global__ __launch_bounds__(128) void scan5(
    const int* __restrict__ nbrG, const uint32_t* __restrict__ scG,
    unsigned* __restrict__ rawnu, float* __restrict__ out)
{
  __shared__ int colors[NV];            // 32 KB
  __shared__ uint32_t scR[32][160];     // 20 KB ring: 320 u16 cands/row
  __shared__ int nbrRing[1024];         // 4 KB: 4 chunks x 8 rows x 32
  __shared__ unsigned bbuf[2][16];
  __shared__ int prod_done, cons_done;

  const int t = threadIdx.x;
  const int lane = t & 63;
  const int ln32 = lane & 31;
  const uint16_t* scR16 = reinterpret_cast<const uint16_t*>(&scR[0][0]);

  for (int i = t; i < NV; i += 128) colors[i] = -1;
  if (t == 0) { colors[0] = 0; prod_done = 0; cons_done = 0; }
  __syncthreads();

  if (t >= 64) {
    // ================= producer wave =================
    for (int pc = 0; pc < 1024; ++pc) {
      while (__hip_atomic_load(&cons_done, __ATOMIC_ACQUIRE, WG_SCOPE) < pc - 3)
        __builtin_amdgcn_s_sleep(1);
      uint32_t x[8], y[8], z[8];
#pragma unroll
      for (int r = 0; r < 8; ++r) {
        const size_t base = (size_t)(pc * 8 + r) * RSTRIDE;   // u32 units
        x[r] = scG[base + lane];
        y[r] = scG[base + 64 + lane];
        z[r] = (lane < 32) ? scG[base + 128 + lane] : 0u;
      }
      const int4 nb4 = *reinterpret_cast<const int4*>(nbrG + pc * 256 + 4 * lane);
#pragma unroll
      for (int r = 0; r < 8; ++r) {
        const int slot = (pc * 8 + r) & 31;
        scR[slot][lane] = x[r];
        scR[slot][64 + lane] = y[r];
        if (lane < 32) scR[slot][128 + lane] = z[r];
      }
      *reinterpret_cast<int4*>(&nbrRing[((pc & 3) << 8) + 4 * lane]) = nb4;
      if (lane == 0)
        __hip_atomic_store(&prod_done, pc + 1, __ATOMIC_RELEASE, WG_SCOPE);
    }
    return;
  }

  // ================= consumer wave =================
  while (__hip_atomic_load(&prod_done, __ATOMIC_ACQUIRE, WG_SCOPE) < 2) {}

  // prologue: build full state for v = 1
  int c0, c1, c2, c3, c4;
  bool sa0, sa1, sa2, sa3, sa4, hf;
  int nbrn;
  {
    c0 = scR16[320 + lane];
    c1 = scR16[320 + 64 + lane];
    c2 = scR16[320 + 128 + lane];
    c3 = scR16[320 + 192 + lane];
    c4 = scR16[320 + 256 + lane];
    const int nb1 = nbrRing[32 + ln32];           // row 1, chunk 0
    bbuf[1][lane & 15] = 0u;
    hf = (__ballot(nb1 == 0) != 0ULL);
    const int cg0 = colors[nb1];
    if (cg0 >= 0) atomicOr(&bbuf[1][cg0 >> 5], 1u << (cg0 & 31));
    sa0 = !((bbuf[1][c0 >> 5] >> (c0 & 31)) & 1u);
    sa1 = !((bbuf[1][c1 >> 5] >> (c1 & 31)) & 1u);
    sa2 = !((bbuf[1][c2 >> 5] >> (c2 & 31)) & 1u);
    sa3 = !((bbuf[1][c3 >> 5] >> (c3 & 31)) & 1u);
    sa4 = !((bbuf[1][c4 >> 5] >> (c4 & 31)) & 1u);
    nbrn = nbrRing[64 + ln32];                    // row 2, chunk 0
  }

  int chosen_prev = 0;
  int n_used = 1;

  for (int v = 1; v < NV; ++v) {
    const int vp1 = (v + 1 < NV) ? v + 1 : NV - 1;
    const int vp2 = (v + 2 < NV) ? v + 2 : NV - 1;

    // ---- chunk sync (1/8 iters) ----
    if ((v & 7) == 7) {
      if (lane == 0)
        __hip_atomic_store(&cons_done, (v + 1) >> 3, __ATOMIC_RELEASE, WG_SCOPE);
      int tgt = ((v + 1) >> 3) + 2;
      tgt = tgt > 1024 ? 1024 : tgt;
      while (__hip_atomic_load(&prod_done, __ATOMIC_ACQUIRE, WG_SCOPE) < tgt) {}
    }

    // ---- prefetch phase: candidates + full mask for v+1 ----
    const int sB = (vp1 & 31) * 320;
    const int n0 = scR16[sB + lane];
    const int n1 = scR16[sB + 64 + lane];
    const int n2 = scR16[sB + 128 + lane];
    const int n3 = scR16[sB + 192 + lane];
    const int n4 = scR16[sB + 256 + lane];
    const int nbrn2 = nbrRing[(((vp2 >> 3) & 3) << 8) + ((vp2 & 7) << 5) + ln32];

    const int nb = vp1 & 1;
    bbuf[nb][lane & 15] = 0u;
    const bool hfn = (__ballot(nbrn == v) != 0ULL);
    const int cgn = colors[nbrn];                 // stale gather (misses only v)
    if (cgn >= 0) atomicOr(&bbuf[nb][cgn >> 5], 1u << (cgn & 31));
    const bool sn0 = !((bbuf[nb][n0 >> 5] >> (n0 & 31)) & 1u);
    const bool sn1 = !((bbuf[nb][n1 >> 5] >> (n1 & 31)) & 1u);
    const bool sn2 = !((bbuf[nb][n2 >> 5] >> (n2 & 31)) & 1u);
    const bool sn3 = !((bbuf[nb][n3 >> 5] >> (n3 & 31)) & 1u);
    const bool sn4 = !((bbuf[nb][n4 >> 5] >> (n4 & 31)) & 1u);

    // ---- critical phase for v: first allowed candidate in sorted order ----
    const int nu = n_used;
    const int fixc = chosen_prev;
    int raw = 256;
    {
      const bool a0 = sa0 && (c0 < nu || c0 == 256) && !(hf && c0 == fixc);
      uint64_t b = __ballot(a0);
      if (b) {
        raw = __builtin_amdgcn_readlane(c0, (int)__builtin_ctzll(b));
      } else {
        const bool a1 = sa1 && (c1 < nu || c1 == 256) && !(hf && c1 == fixc);
        b = __ballot(a1);
        if (b) {
          raw = __builtin_amdgcn_readlane(c1, (int)__builtin_ctzll(b));
        } else {
          const bool a2 = sa2 && (c2 < nu || c2 == 256) && !(hf && c2 == fixc);
          b = __ballot(a2);
          if (b) {
            raw = __builtin_amdgcn_readlane(c2, (int)__builtin_ctzll(b));
          } else {
            const bool a3 = sa3 && (c3 < nu || c3 == 256) && !(hf && c3 == fixc);
            b = __ballot(a3);
            if (b) {
              raw = __builtin_amdgcn_readlane(c3, (int)__builtin_ctzll(b));
            } else {
              const bool a4 = sa4 && (c4 < nu || c4 == 256) && !(hf && c4 == fixc);
              b = __ballot(a4);
              if (b) raw = __builtin_amdgcn_readlane(c4, (int)__builtin_ctzll(b));
            }
          }
        }
      }
    }

    const bool isnew = (raw == 256);
    const int chosen = isnew ? nu : raw;
    if (isnew) ++n_used;
    if (lane == 0) {
      colors[v] = chosen;
      rawnu[v] = (unsigned)raw | ((unsigned)nu << 16);
    }

    // ---- shift pipelined state ----
    c0 = n0; c1 = n1; c2 = n2; c3 = n3; c4 = n4;
    sa0 = sn0; sa1 = sn1; sa2 = sn2; sa3 = sn3; sa4 = sn4;
    hf = hfn; nbrn = nbrn2; chosen_prev = chosen;
  }

  for (int i = lane; i < NV; i += 64) out[i] = (float)colors[i];
}

// ---------------------------------------------------------------------------
// K4: parallel logp recomputation (unchanged from round 4).
// ---------------------------------------------------------------------------
__global__ __launch_bounds__(256) void logp_part(
    const float* __restrict__ outF, const int* __restrict__ nbrG,
    const float* __restrict__ er, const unsigned* __restrict__ rawnu,
    double* __restrict__ partd)
{
  __shared__ unsigned bb[4][16];
  const int t = threadIdx.x;
  const int w = t >> 6;
  const int lane = t & 63;
  const int ln32 = lane & 31;
  const int b = blockIdx.x;

  double a = 0.0;
  for (int i = 0; i < 32; ++i) {
    const int v = b * 128 + w * 32 + i;
    if (v == 0) continue;
    const unsigned val = rawnu[v];
    const int raw = (int)(val & 0xFFFFu);
    const int nu  = (int)(val >> 16);

    bb[w][lane & 15] = 0u;
    const int u = nbrG[(size_t)v * DEG + ln32];
    const int cu = (u < v) ? (int)outF[u] : -1;
    if (cu >= 0) atomicOr(&bb[w][cu >> 5], 1u << (cu & 31));
    unsigned bwp[4];
#pragma unroll
    for (int j = 0; j < 4; ++j) bwp[j] = bb[w][(lane >> 5) + 2 * j];
    const unsigned bw8 = bb[w][8];

    const size_t base = (size_t)v * RSTRIDE;
    bool mk[4];
    float e[4];
#pragma unroll
    for (int j = 0; j < 4; ++j) {
      const int c = lane + 64 * j;
      mk[j] = (((bwp[j] >> ln32) & 1u) != 0u) || (c >= nu);
      e[j] = mk[j] ? 0.f : er[base + c];
    }
    const bool mkX = ((bw8 & 1u) != 0u);
    const float eX = er[base + 256];
    const float e4 = (!mkX && lane == 0) ? eX : 0.f;

    float S = ((e[0] + e[1]) + (e[2] + e[3])) + e4;
    SRED(0x111) SRED(0x112) SRED(0x114) SRED(0x118) SRED(0x142) SRED(0x143)
    const float Sall = __int_as_float(
        __builtin_amdgcn_readlane(__float_as_int(S), 63));

    const bool isnew = (raw == 256);
    const int jsel  = isnew ? 4 : (raw >> 6);
    const int owner = isnew ? 0 : (raw & 63);
    const float cand = (jsel == 0) ? e[0] : (jsel == 1) ? e[1]
                     : (jsel == 2) ? e[2] : (jsel == 3) ? e[3] : e4;
    const float praw = __int_as_float(
        __builtin_amdgcn_readlane(__float_as_int(cand), owner));

    const float p = praw / Sall;
    a += (double)(logf(p + 1e-8f) - logf(1e-8f));
  }
  if (lane == 0) partd[b * 4 + w] = a;
}

__global__ __launch_bounds__(64) void finalize(
    const double* __restrict__ partd, const unsigned* __restrict__ rawnu,
    const float* __restrict__ baseline, float* __restrict__ out)
{
  if (threadIdx.x == 0) {
    double lp = 0.0;
    for (int i = 0; i < 256; ++i) lp += partd[i];
    const unsigned val = rawnu[NV - 1];
    const unsigned nf = (val >> 16) + (((val & 0xFFFFu) == 256u) ? 1u : 0u);
    out[NV] = ((float)nf - baseline[0]) * (float)lp / 8192.0f;
  }
}

// ---------------------------------------------------------------------------
extern "C" void kernel_launch(void* const* d_in, const int* in_sizes, int n_in,
                              void* d_out, int out_size, void* d_ws, size_t ws_size,
                              hipStream_t stream) {
  const float* emb      = (const float*)d_in[0];
  const int*   nbr      = (const int*)d_in[1];
  const float* W1       = (const float*)d_in[2];
  const float* b1       = (const float*)d_in[3];
  const float* W2       = (const float*)d_in[4];
  const float* b2       = (const float*)d_in[5];
  const float* W3       = (const float*)d_in[6];
  const float* b3       = (const float*)d_in[7];
  const float* baseline = (const float*)d_in[8];
  float* out = (float*)d_out;

  char* ws = (char*)d_ws;
  float* g     = (float*)ws;                               // 2 KB
  float* plbuf = (float*)(ws + 2048);                      // 8192*260*4 B
  float* erbuf = (float*)(ws + 2048 + NV * RSTRIDE * 4);   // 8192*260*4 B
  float* part  = erbuf;  // alias: consumed by colmean_fin BEFORE mlp3g writes er
  // rawnu/partd alias long-dead head of plbuf (consumed before writes land):
  unsigned* rawnu = (unsigned*)(ws + 2048);                // 32 KB
  double*   partd = (double*)(ws + 2048 + 65536);          // 2 KB

  colmean_part<<<64, 256, 0, stream>>>(emb, part);
  colmean_fin<<<1, 256, 0, stream>>>(part, g);
  mlp3g<<<NV / TV, 256, 0, stream>>>(emb, g, W1, b1, W2, b2, W3, b3, plbuf, erbuf);
  sortrows<<<NV / 4, 256, 0, stream>>>(plbuf);
  scan5<<<1, 128, 0, stream>>>(nbr, (const uint32_t*)plbuf, rawnu, out);
  logp_part<<<64, 256, 0, stream>>>((const float*)out, nbr, erbuf, rawnu, partd);
  finalize<<<1, 64, 0, stream>>>(partd, rawnu, baseline, out);
}